// Round 4
// baseline (1197.503 us; speedup 1.0000x reference)
//
#include <hip/hip_runtime.h>
#include <cstdint>
#include <cstddef>

#define EPSF 1e-6f
#define BN_EPSF 1e-5f

constexpr int Bb = 4;
constexpr int Nn = 8192;
constexpr int KK = 20;
constexpr int SEG = 8;            // knn candidate segments
constexpr int SEGLEN = Nn / SEG;  // 1024
constexpr int BUF = 8;            // per-lane candidate buffer (LDS slots)

// ---------------- workspace layout (float elements) ----------------
constexpr size_t KNN0_OFF = 0;              // B*8*N*20 u32 = 5,242,880
constexpr size_t KNN1_OFF = 5242880;        // B*4*N*20 u32 = 2,621,440 (ends 7,864,320)
constexpr size_t X1_OFF  = 0;               // B*21*3*N = 2,064,384
constexpr size_t X2_OFF  = 2064384;
constexpr size_t X3_OFF  = 4128768;         // B*42*3*N = 4,128,768 (ends 8,257,536)
constexpr size_t Z1_OFF  = 0;               // B*85*3*N = 8,355,840
constexpr size_t X4_OFF  = 8355840;         // 8,355,840
constexpr size_t IDX_OFF = 16711680;        // B*N*K ints = 655,360
constexpr size_t Z2_OFF  = 17367040;        // 4,128,768
constexpr size_t Z3_OFF  = 21495808;        // B*3*3*N = 294,912
constexpr size_t ACC_OFF = 21790720;        // 1024
constexpr size_t XM_OFF  = 21791744;        // 1020
constexpr size_t BF_OFF  = 21792764;        // 1020
constexpr size_t BD_OFF  = 21793784;        // 1020
constexpr size_t PB_OFF  = 21794816;        // 4*128*510 = 261,120 (s9 partials)

__device__ __forceinline__ float wave_sum(float v) {
#pragma unroll
  for (int off = 32; off; off >>= 1) v += __shfl_xor(v, off, 64);
  return v;
}
__device__ __forceinline__ float wave_max(float v) {
#pragma unroll
  for (int off = 32; off; off >>= 1) v = fmaxf(v, __shfl_xor(v, off, 64));
  return v;
}
__device__ __forceinline__ uint32_t umin32(uint32_t a, uint32_t b) { return a < b ? a : b; }
__device__ __forceinline__ uint32_t umax32(uint32_t a, uint32_t b) { return a < b ? b : a; }

// ---------------- zero accumulators ----------------
__global__ __launch_bounds__(1024) void zero_acc(float* __restrict__ a) {
  a[threadIdx.x] = 0.f;
}

// ---------------- KNN: buffered top-20 select over one segment ----------------
// key = (f32 dist bits & 0xFFFFE000) | idx(13b) -> absolute order, merge-tree associative.
__global__ __launch_bounds__(128) void knn_kernel(const float* __restrict__ pts,
                                                  uint32_t* __restrict__ knnp) {
  __shared__ float4 tile[SEGLEN];          // 16 KB
  __shared__ uint32_t buf[BUF * 128];      // 4 KB; buf[slot*128+tid] -> 2 lanes/bank, free
  const int tid = threadIdx.x;
  const int n = blockIdx.x * 128 + tid;
  const int b = blockIdx.y;
  const int s = blockIdx.z;
  const float* pb = pts + (size_t)b * Nn * 3;

  for (int i = tid; i < SEGLEN; i += 128) {
    const float* p = pb + (size_t)(s * SEGLEN + i) * 3;
    tile[i] = make_float4(p[0], p[1], p[2], 0.f);
  }
  const float qx = pb[n * 3 + 0], qy = pb[n * 3 + 1], qz = pb[n * 3 + 2];
  __syncthreads();

  uint32_t keys[KK];
#pragma unroll
  for (int j = 0; j < KK; ++j) keys[j] = 0xFFFFFFFFu;

  const int base = s * SEGLEN;

  // ---- warm-up: first 64 candidates, direct min/max-chain insert ----
#pragma unroll 4
  for (int j = 0; j < 64; ++j) {
    const float4 c = tile[j];
    const float dx = qx - c.x, dy = qy - c.y, dz = qz - c.z;
    const float d2 = dx * dx + dy * dy + dz * dz;
    uint32_t mx = (__float_as_uint(d2) & 0xFFFFE000u) | (uint32_t)(base + j);
#pragma unroll
    for (int q = 0; q < KK; ++q) {
      const uint32_t mn = umin32(keys[q], mx);
      mx = umax32(keys[q], mx);
      keys[q] = mn;
    }
  }

  uint32_t thresh = keys[KK - 1];
  int cnt = 0;

  // ---- main loop: screen against thresh, buffer survivors, merge rarely ----
  for (int j0 = 64; j0 < SEGLEN; j0 += 4) {
#pragma unroll
    for (int u = 0; u < 4; ++u) {
      const int j = j0 + u;
      const float4 c = tile[j];
      const float dx = qx - c.x, dy = qy - c.y, dz = qz - c.z;
      const float d2 = dx * dx + dy * dy + dz * dz;
      const uint32_t key = (__float_as_uint(d2) & 0xFFFFE000u) | (uint32_t)(base + j);
      if (key < thresh) {
        buf[cnt * 128 + tid] = key;
        ++cnt;
      }
    }
    if (__any(cnt > BUF - 4)) {
#pragma unroll
      for (int i = 0; i < BUF; ++i) {
        uint32_t mx = (i < cnt) ? buf[i * 128 + tid] : 0xFFFFFFFFu;
#pragma unroll
        for (int q = 0; q < KK; ++q) {
          const uint32_t mn = umin32(keys[q], mx);
          mx = umax32(keys[q], mx);
          keys[q] = mn;
        }
      }
      cnt = 0;
      thresh = keys[KK - 1];
    }
  }
  // ---- final flush ----
#pragma unroll
  for (int i = 0; i < BUF; ++i) {
    uint32_t mx = (i < cnt) ? buf[i * 128 + tid] : 0xFFFFFFFFu;
#pragma unroll
    for (int q = 0; q < KK; ++q) {
      const uint32_t mn = umin32(keys[q], mx);
      mx = umax32(keys[q], mx);
      keys[q] = mn;
    }
  }

  // list-major layout: [(b*SEG+s)][j][n] -> coalesced stores per j
  uint32_t* op = knnp + ((size_t)(b * SEG + s) * KK) * Nn + n;
#pragma unroll
  for (int j = 0; j < KK; ++j) op[(size_t)j * Nn] = keys[j];
}

// ---------------- merge tree passes ----------------
template <int LIN>
__global__ __launch_bounds__(256) void merge_pass(const uint32_t* __restrict__ in,
                                                  uint32_t* __restrict__ out) {
  constexpr int LOUT = LIN / 2;
  const int t = blockIdx.x * 256 + threadIdx.x;  // B*N*LOUT threads
  const int n = t & (Nn - 1);
  const int r = t >> 13;
  const int j = r % LOUT, b = r / LOUT;
  const uint32_t* p0 = in + ((size_t)(b * LIN + 2 * j) * KK) * Nn + n;
  const uint32_t* p1 = in + ((size_t)(b * LIN + 2 * j + 1) * KK) * Nn + n;
  uint32_t* op = out + ((size_t)(b * LOUT + j) * KK) * Nn + n;
  int i0 = 0, i1 = 0;
  uint32_t k0 = p0[0], k1 = p1[0];
#pragma unroll
  for (int m = 0; m < KK; ++m) {
    uint32_t k;
    if (k0 <= k1) { k = k0; ++i0; k0 = (i0 < KK) ? p0[(size_t)i0 * Nn] : 0xFFFFFFFFu; }
    else          { k = k1; ++i1; k1 = (i1 < KK) ? p1[(size_t)i1 * Nn] : 0xFFFFFFFFu; }
    op[(size_t)m * Nn] = k;
  }
}

__global__ __launch_bounds__(256) void merge_final(const uint32_t* __restrict__ in,
                                                   int* __restrict__ idx) {
  const int t = blockIdx.x * 256 + threadIdx.x;  // B*N threads
  const int n = t & (Nn - 1), b = t >> 13;
  const uint32_t* p0 = in + ((size_t)(b * 2 + 0) * KK) * Nn + n;
  const uint32_t* p1 = in + ((size_t)(b * 2 + 1) * KK) * Nn + n;
  int* op = idx + (size_t)t * KK;
  int i0 = 0, i1 = 0;
  uint32_t k0 = p0[0], k1 = p1[0];
#pragma unroll
  for (int m = 0; m < KK; ++m) {
    uint32_t k;
    if (k0 <= k1) { k = k0; ++i0; k0 = (i0 < KK) ? p0[(size_t)i0 * Nn] : 0xFFFFFFFFu; }
    else          { k = k1; ++i1; k1 = (i1 < KK) ? p1[(size_t)i1 * Nn] : 0xFFFFFFFFu; }
    op[m] = (int)(k & 8191u);
  }
}

// ---------------- stage 1: feature-cross + LLR(21) ----------------
__global__ __launch_bounds__(256) void s1_stats(const float* __restrict__ pts,
                                                const int* __restrict__ idx,
                                                const float* __restrict__ wf,
                                                float* __restrict__ acc) {
  __shared__ float lacc[42];
  const int tid = threadIdx.x;
  for (int i = tid; i < 42; i += 256) lacc[i] = 0.f;
  __syncthreads();
  const int t = blockIdx.x * 256 + tid;  // 0..B*N*K-1
  const int site = t / KK;
  const int n = site & (Nn - 1), b = site >> 13;
  const int m = idx[t];
  const float* pb = pts + (size_t)b * Nn * 3;
  const float ax = pb[m * 3 + 0], ay = pb[m * 3 + 1], az = pb[m * 3 + 2];
  const float cx = pb[n * 3 + 0], cy = pb[n * 3 + 1], cz = pb[n * 3 + 2];
  const float e0x = ax - cx, e0y = ay - cy, e0z = az - cz;
  const float e2x = ay * cz - az * cy, e2y = az * cx - ax * cz, e2z = ax * cy - ay * cx;
#pragma unroll
  for (int o = 0; o < 21; ++o) {
    const float w0 = wf[o * 3 + 0], w1 = wf[o * 3 + 1], w2 = wf[o * 3 + 2];
    const float px = w0 * e0x + w1 * cx + w2 * e2x;
    const float py = w0 * e0y + w1 * cy + w2 * e2y;
    const float pz = w0 * e0z + w1 * cz + w2 * e2z;
    const float nrm = sqrtf(px * px + py * py + pz * pz) + EPSF;
    const float s1 = wave_sum(nrm);
    const float s2 = wave_sum(nrm * nrm);
    if ((tid & 63) == 0) { atomicAdd(&lacc[o], s1); atomicAdd(&lacc[21 + o], s2); }
  }
  __syncthreads();
  for (int i = tid; i < 42; i += 256) atomicAdd(&acc[i], lacc[i]);
}

// single pass over all 21 output channels; gathers each neighbor once
__global__ __launch_bounds__(128) void s1_apply(const float* __restrict__ pts,
                                                const int* __restrict__ idx,
                                                const float* __restrict__ wf,
                                                const float* __restrict__ wd,
                                                const float* __restrict__ acc,
                                                float* __restrict__ x1) {
  const int t = blockIdx.x * 128 + threadIdx.x;  // site 0..B*N-1
  const int n = t & (Nn - 1), b = t >> 13;
  const float* pb = pts + (size_t)b * Nn * 3;
  const float cx = pb[n * 3 + 0], cy = pb[n * 3 + 1], cz = pb[n * 3 + 2];
  const float inv_cnt = 1.f / (float)(Bb * Nn * KK);
  float accu[21][3];
#pragma unroll
  for (int j = 0; j < 21; ++j) { accu[j][0] = 0.f; accu[j][1] = 0.f; accu[j][2] = 0.f; }
  for (int k = 0; k < KK; ++k) {
    const int m = idx[(size_t)t * KK + k];
    const float ax = pb[m * 3 + 0], ay = pb[m * 3 + 1], az = pb[m * 3 + 2];
    const float e0x = ax - cx, e0y = ay - cy, e0z = az - cz;
    const float e2x = ay * cz - az * cy, e2y = az * cx - ax * cz, e2z = ax * cy - ay * cx;
#pragma unroll
    for (int o = 0; o < 21; ++o) {
      const float wf0 = wf[o * 3 + 0], wf1 = wf[o * 3 + 1], wf2 = wf[o * 3 + 2];
      const float px = wf0 * e0x + wf1 * cx + wf2 * e2x;
      const float py = wf0 * e0y + wf1 * cy + wf2 * e2y;
      const float pz = wf0 * e0z + wf1 * cz + wf2 * e2z;
      const float nrm = sqrtf(px * px + py * py + pz * pz) + EPSF;
      const float mn = acc[o] * inv_cnt;
      const float vr = acc[21 + o] * inv_cnt - mn * mn;
      const float factor = (nrm - mn) * rsqrtf(vr + BN_EPSF) / nrm;
      const float q0 = px * factor, q1 = py * factor, q2 = pz * factor;
      const float wd0 = wd[o * 3 + 0], wd1 = wd[o * 3 + 1], wd2 = wd[o * 3 + 2];
      const float dx = wd0 * e0x + wd1 * cx + wd2 * e2x;
      const float dy = wd0 * e0y + wd1 * cy + wd2 * e2y;
      const float dz = wd0 * e0z + wd1 * cz + wd2 * e2z;
      const float dot = q0 * dx + q1 * dy + q2 * dz;
      const float dsq = dx * dx + dy * dy + dz * dz;
      const float corr = (dot < 0.f) ? dot / (dsq + EPSF) : 0.f;
      accu[o][0] += q0 - corr * dx;
      accu[o][1] += q1 - corr * dy;
      accu[o][2] += q2 - corr * dz;
    }
  }
  const float sc = 1.f / (float)KK;
  float* ob = x1 + (size_t)b * 21 * 3 * Nn + n;
#pragma unroll
  for (int o = 0; o < 21; ++o) {
    ob[(o * 3 + 0) * Nn] = accu[o][0] * sc;
    ob[(o * 3 + 1) * Nn] = accu[o][1] * sc;
    ob[(o * 3 + 2) * Nn] = accu[o][2] * sc;
  }
}

// ---------------- generic VN layer: stats + apply (o-tile = blockIdx.y) ----------------
template <int CIN, int COUT, int OT, bool HAS_BIAS>
__global__ __launch_bounds__(128) void vn_stats(const float* __restrict__ X,
                                                const float* __restrict__ Wf, int ws,
                                                const float* __restrict__ biasF,
                                                float* __restrict__ acc) {
  __shared__ float lacc[2 * OT];
  const int tid = threadIdx.x;
  if (tid < 2 * OT) lacc[tid] = 0.f;
  __syncthreads();
  const int o0 = blockIdx.y * OT;
  const int t = blockIdx.x * 128 + tid;
  const int n = t & (Nn - 1), b = t >> 13;
  const float* xb = X + (size_t)b * CIN * 3 * Nn + n;
  float p[OT][3];
#pragma unroll
  for (int j = 0; j < OT; ++j)
#pragma unroll
    for (int dd = 0; dd < 3; ++dd)
      p[j][dd] = HAS_BIAS ? biasF[((size_t)b * COUT + o0 + j) * 3 + dd] : 0.f;
  for (int c = 0; c < CIN; ++c) {
    const float x0 = xb[(c * 3 + 0) * Nn];
    const float x1v = xb[(c * 3 + 1) * Nn];
    const float x2v = xb[(c * 3 + 2) * Nn];
#pragma unroll
    for (int j = 0; j < OT; ++j) {
      const float wv = Wf[(o0 + j) * ws + c];
      p[j][0] += wv * x0; p[j][1] += wv * x1v; p[j][2] += wv * x2v;
    }
  }
#pragma unroll
  for (int j = 0; j < OT; ++j) {
    const float nrm = sqrtf(p[j][0] * p[j][0] + p[j][1] * p[j][1] + p[j][2] * p[j][2]) + EPSF;
    const float s1 = wave_sum(nrm);
    const float s2 = wave_sum(nrm * nrm);
    if ((tid & 63) == 0) { atomicAdd(&lacc[j], s1); atomicAdd(&lacc[OT + j], s2); }
  }
  __syncthreads();
  if (tid < 2 * OT) {
    const int g = (tid < OT) ? (o0 + tid) : (COUT + o0 + (tid - OT));
    atomicAdd(&acc[g], lacc[tid]);
  }
}

template <int CIN, int COUT, int OT, bool HAS_BIAS, bool DO_LLR>
__global__ __launch_bounds__(128) void vn_apply(const float* __restrict__ X,
                                                const float* __restrict__ Wf,
                                                const float* __restrict__ Wd, int ws,
                                                const float* __restrict__ biasF,
                                                const float* __restrict__ biasD,
                                                const float* __restrict__ acc, float cntinv,
                                                float* __restrict__ OUT) {
  const int o0 = blockIdx.y * OT;
  const int t = blockIdx.x * 128 + threadIdx.x;
  const int n = t & (Nn - 1), b = t >> 13;
  const float* xb = X + (size_t)b * CIN * 3 * Nn + n;
  float* ob = OUT + (size_t)b * COUT * 3 * Nn + n;
  float p[OT][3], dv[OT][3];
#pragma unroll
  for (int j = 0; j < OT; ++j)
#pragma unroll
    for (int dd = 0; dd < 3; ++dd) {
      p[j][dd] = HAS_BIAS ? biasF[((size_t)b * COUT + o0 + j) * 3 + dd] : 0.f;
      if constexpr (DO_LLR)
        dv[j][dd] = HAS_BIAS ? biasD[((size_t)b * COUT + o0 + j) * 3 + dd] : 0.f;
      else
        dv[j][dd] = 0.f;
    }
  for (int c = 0; c < CIN; ++c) {
    const float x0 = xb[(c * 3 + 0) * Nn];
    const float x1v = xb[(c * 3 + 1) * Nn];
    const float x2v = xb[(c * 3 + 2) * Nn];
#pragma unroll
    for (int j = 0; j < OT; ++j) {
      const float wfv = Wf[(o0 + j) * ws + c];
      p[j][0] += wfv * x0; p[j][1] += wfv * x1v; p[j][2] += wfv * x2v;
      if constexpr (DO_LLR) {
        const float wdv = Wd[(o0 + j) * ws + c];
        dv[j][0] += wdv * x0; dv[j][1] += wdv * x1v; dv[j][2] += wdv * x2v;
      }
    }
  }
#pragma unroll
  for (int j = 0; j < OT; ++j) {
    const int o = o0 + j;
    const float nrm = sqrtf(p[j][0] * p[j][0] + p[j][1] * p[j][1] + p[j][2] * p[j][2]) + EPSF;
    const float mn = acc[o] * cntinv;
    const float vr = acc[COUT + o] * cntinv - mn * mn;
    const float factor = (nrm - mn) * rsqrtf(vr + BN_EPSF) / nrm;
    float r0 = p[j][0] * factor, r1 = p[j][1] * factor, r2 = p[j][2] * factor;
    if constexpr (DO_LLR) {
      const float dot = r0 * dv[j][0] + r1 * dv[j][1] + r2 * dv[j][2];
      const float dsq = dv[j][0] * dv[j][0] + dv[j][1] * dv[j][1] + dv[j][2] * dv[j][2];
      const float corr = (dot < 0.f) ? dot / (dsq + EPSF) : 0.f;
      r0 -= corr * dv[j][0]; r1 -= corr * dv[j][1]; r2 -= corr * dv[j][2];
    }
    ob[(o * 3 + 0) * Nn] = r0;
    ob[(o * 3 + 1) * Nn] = r1;
    ob[(o * 3 + 2) * Nn] = r2;
  }
}

// ---------------- stage 5: mean over N, bias precompute, small outputs ----------------
__global__ __launch_bounds__(256) void s5_mean(const float* __restrict__ x4,
                                               float* __restrict__ xm,
                                               float* __restrict__ out) {
  const int row = blockIdx.x;  // 0..1019 = b*255 + c*3 + dd
  const int b = row / 255, rcd = row % 255;
  const float* src = x4 + (size_t)b * 255 * Nn + (size_t)rcd * Nn;
  float s = 0.f;
  for (int n = threadIdx.x; n < Nn; n += 256) s += src[n];
  s = wave_sum(s);
  __shared__ float wsum[4];
  if ((threadIdx.x & 63) == 0) wsum[threadIdx.x >> 6] = s;
  __syncthreads();
  if (threadIdx.x == 0) {
    const float mv = (wsum[0] + wsum[1] + wsum[2] + wsum[3]) * (1.f / (float)Nn);
    xm[row] = mv;
    out[2040 + row] = mv;  // x_mean_out
  }
}

__global__ __launch_bounds__(256) void s5_bias(const float* __restrict__ xm,
                                               const float* __restrict__ ws1f,
                                               const float* __restrict__ ws1d,
                                               float* __restrict__ biasF,
                                               float* __restrict__ biasD,
                                               float* __restrict__ out) {
  const int t = blockIdx.x * 256 + threadIdx.x;
  if (t < 1020) {
    const int b = t / 255, r = t % 255, o = r / 3, dd = r % 3;
    float sf = 0.f, sd = 0.f;
    for (int c = 0; c < 85; ++c) {
      const float xv = xm[(b * 85 + c) * 3 + dd];
      sf += ws1f[o * 170 + 85 + c] * xv;
      sd += ws1d[o * 170 + 85 + c] * xv;
    }
    biasF[t] = sf;
    biasD[t] = sd;
  }
  if (t < 340) {
    const int b = t / 85, c = t % 85;
    out[3060 + t] = (xm[(b * 85 + c) * 3 + 0] + xm[(b * 85 + c) * 3 + 1] +
                     xm[(b * 85 + c) * 3 + 2]) * (1.f / 3.f);  // center_loc
  }
}

// ---------------- stage 8: z3 = wlin · z2 ----------------
__global__ __launch_bounds__(128) void s8_z3(const float* __restrict__ z2,
                                             const float* __restrict__ wlin,
                                             float* __restrict__ z3) {
  const int t = blockIdx.x * 128 + threadIdx.x;
  const int n = t & (Nn - 1), b = t >> 13;
  const float* zb = z2 + (size_t)b * 42 * 3 * Nn + n;
  float accv[3][3];
#pragma unroll
  for (int o = 0; o < 3; ++o)
#pragma unroll
    for (int dd = 0; dd < 3; ++dd) accv[o][dd] = 0.f;
  for (int c = 0; c < 42; ++c) {
    const float x0 = zb[(c * 3 + 0) * Nn];
    const float x1v = zb[(c * 3 + 1) * Nn];
    const float x2v = zb[(c * 3 + 2) * Nn];
#pragma unroll
    for (int o = 0; o < 3; ++o) {
      const float wv = wlin[o * 42 + c];
      accv[o][0] += wv * x0; accv[o][1] += wv * x1v; accv[o][2] += wv * x2v;
    }
  }
  float* ob = z3 + (size_t)b * 9 * Nn + n;
#pragma unroll
  for (int o = 0; o < 3; ++o)
#pragma unroll
    for (int dd = 0; dd < 3; ++dd) ob[(o * 3 + dd) * Nn] = accv[o][dd];
}

// ---------------- stage 9: x_std + max over N (single read of x4/z3) ----------------
__global__ __launch_bounds__(256) void s9_partial(const float* __restrict__ x4,
                                                  const float* __restrict__ xm,
                                                  const float* __restrict__ z3,
                                                  float* __restrict__ pbuf) {
  const int tid = threadIdx.x;
  const int n = blockIdx.x * 256 + tid;  // chunk of 256 n's
  const int b = blockIdx.y;
  const int w = tid >> 6;
  const float* zb = z3 + (size_t)b * 9 * Nn + n;
  float zk[3][3];
#pragma unroll
  for (int k = 0; k < 3; ++k)
#pragma unroll
    for (int j = 0; j < 3; ++j) zk[k][j] = zb[(k * 3 + j) * Nn];
  const float* xb = x4 + (size_t)b * 255 * Nn + n;
  float* pbw = pbuf + ((size_t)(b * 32 + blockIdx.x) * 4 + w) * 510;
  for (int i = 0; i < 170; ++i) {
    float xj0, xj1, xj2;
    if (i < 85) {
      xj0 = xb[(i * 3 + 0) * Nn];
      xj1 = xb[(i * 3 + 1) * Nn];
      xj2 = xb[(i * 3 + 2) * Nn];
    } else {
      xj0 = xm[(b * 85 + (i - 85)) * 3 + 0];
      xj1 = xm[(b * 85 + (i - 85)) * 3 + 1];
      xj2 = xm[(b * 85 + (i - 85)) * 3 + 2];
    }
#pragma unroll
    for (int k = 0; k < 3; ++k) {
      float v = xj0 * zk[k][0] + xj1 * zk[k][1] + xj2 * zk[k][2];
      v = wave_max(v);
      if ((tid & 63) == 0) pbw[i * 3 + k] = v;
    }
  }
}

__global__ __launch_bounds__(512) void s9_reduce(const float* __restrict__ pbuf,
                                                 float* __restrict__ out) {
  const int b = blockIdx.x;
  const int r = threadIdx.x;
  if (r < 510) {
    float m = -3.402823466e38f;
    for (int c = 0; c < 128; ++c) m = fmaxf(m, pbuf[((size_t)(b * 128 + c)) * 510 + r]);
    out[b * 510 + r] = m;
  }
}

// ---------------- launch ----------------
extern "C" void kernel_launch(void* const* d_in, const int* in_sizes, int n_in,
                              void* d_out, int out_size, void* d_ws, size_t ws_size,
                              hipStream_t stream) {
  const float* pts   = (const float*)d_in[0];
  const float* wposf = (const float*)d_in[1];
  const float* wposd = (const float*)d_in[2];
  const float* w1f   = (const float*)d_in[3];
  const float* w1d   = (const float*)d_in[4];
  const float* w2f   = (const float*)d_in[5];
  const float* w2d   = (const float*)d_in[6];
  const float* w3    = (const float*)d_in[7];
  const float* ws1f  = (const float*)d_in[8];
  const float* ws1d  = (const float*)d_in[9];
  const float* ws2f  = (const float*)d_in[10];
  const float* ws2d  = (const float*)d_in[11];
  const float* wlin  = (const float*)d_in[12];
  float* out = (float*)d_out;
  float* wsf = (float*)d_ws;

  uint32_t* knnp0 = (uint32_t*)(wsf + KNN0_OFF);
  uint32_t* knnp1 = (uint32_t*)(wsf + KNN1_OFF);
  float* x1 = wsf + X1_OFF;
  float* x2 = wsf + X2_OFF;
  float* x3 = wsf + X3_OFF;
  float* z1 = wsf + Z1_OFF;
  float* x4 = wsf + X4_OFF;
  int* idx  = (int*)(wsf + IDX_OFF);
  float* z2 = wsf + Z2_OFF;
  float* z3 = wsf + Z3_OFF;
  float* acc = wsf + ACC_OFF;
  float* xm = wsf + XM_OFF;
  float* biasF = wsf + BF_OFF;
  float* biasD = wsf + BD_OFF;
  float* pbuf = wsf + PB_OFF;

  const float inv_sites = 1.f / (float)(Bb * Nn);

  zero_acc<<<1, 1024, 0, stream>>>(acc);
  knn_kernel<<<dim3(Nn / 128, Bb, SEG), 128, 0, stream>>>(pts, knnp0);
  merge_pass<8><<<Bb * Nn * 4 / 256, 256, 0, stream>>>(knnp0, knnp1);
  merge_pass<4><<<Bb * Nn * 2 / 256, 256, 0, stream>>>(knnp1, knnp0);
  merge_final<<<Bb * Nn / 256, 256, 0, stream>>>(knnp0, idx);

  s1_stats<<<Bb * Nn * KK / 256, 256, 0, stream>>>(pts, idx, wposf, acc + 0);
  s1_apply<<<Bb * Nn / 128, 128, 0, stream>>>(pts, idx, wposf, wposd, acc + 0, x1);

  vn_stats<21, 21, 7, false><<<dim3(Bb * Nn / 128, 3), 128, 0, stream>>>(x1, w1f, 21, nullptr, acc + 64);
  vn_apply<21, 21, 7, false, true><<<dim3(Bb * Nn / 128, 3), 128, 0, stream>>>(
      x1, w1f, w1d, 21, nullptr, nullptr, acc + 64, inv_sites, x2);

  vn_stats<21, 42, 7, false><<<dim3(Bb * Nn / 128, 6), 128, 0, stream>>>(x2, w2f, 42, nullptr, acc + 128);
  vn_apply<21, 42, 7, false, true><<<dim3(Bb * Nn / 128, 6), 128, 0, stream>>>(
      x2, w2f, w2d, 42, nullptr, nullptr, acc + 128, inv_sites, x3);

  vn_stats<42, 85, 17, false><<<dim3(Bb * Nn / 128, 5), 128, 0, stream>>>(x3, w3, 42, nullptr, acc + 256);
  vn_apply<42, 85, 17, false, false><<<dim3(Bb * Nn / 128, 5), 128, 0, stream>>>(
      x3, w3, w3, 42, nullptr, nullptr, acc + 256, inv_sites, x4);

  s5_mean<<<Bb * 255, 256, 0, stream>>>(x4, xm, out);
  s5_bias<<<4, 256, 0, stream>>>(xm, ws1f, ws1d, biasF, biasD, out);

  vn_stats<85, 85, 17, true><<<dim3(Bb * Nn / 128, 5), 128, 0, stream>>>(x4, ws1f, 170, biasF, acc + 512);
  vn_apply<85, 85, 17, true, true><<<dim3(Bb * Nn / 128, 5), 128, 0, stream>>>(
      x4, ws1f, ws1d, 170, biasF, biasD, acc + 512, inv_sites, z1);

  vn_stats<85, 42, 14, false><<<dim3(Bb * Nn / 128, 3), 128, 0, stream>>>(z1, ws2f, 85, nullptr, acc + 768);
  vn_apply<85, 42, 14, false, true><<<dim3(Bb * Nn / 128, 3), 128, 0, stream>>>(
      z1, ws2f, ws2d, 85, nullptr, nullptr, acc + 768, inv_sites, z2);

  s8_z3<<<Bb * Nn / 128, 128, 0, stream>>>(z2, wlin, z3);
  s9_partial<<<dim3(32, Bb), 256, 0, stream>>>(x4, xm, z3, pbuf);
  s9_reduce<<<Bb, 512, 0, stream>>>(pbuf, out);
}

// Round 5
// 1160.356 us; speedup vs baseline: 1.0320x; 1.0320x over previous
//
#include <hip/hip_runtime.h>
#include <cstdint>
#include <cstddef>

#define EPSF 1e-6f
#define BN_EPSF 1e-5f

constexpr int Bb = 4;
constexpr int Nn = 8192;
constexpr int KK = 20;
constexpr int SEG = 8;            // knn candidate segments
constexpr int SEGLEN = Nn / SEG;  // 1024
constexpr int BUF = 16;           // per-lane candidate buffer (LDS slots)

// ---------------- workspace layout (float elements) ----------------
constexpr size_t KNN0_OFF = 0;              // B*8*N*20 u32 = 5,242,880
constexpr size_t KNN1_OFF = 5242880;        // B*4*N*20 u32 = 2,621,440 (ends 7,864,320)
constexpr size_t X1_OFF  = 0;               // B*21*3*N = 2,064,384
constexpr size_t X2_OFF  = 2064384;
constexpr size_t X3_OFF  = 4128768;         // B*42*3*N = 4,128,768 (ends 8,257,536)
constexpr size_t Z1_OFF  = 0;               // B*85*3*N = 8,355,840
constexpr size_t X4_OFF  = 8355840;         // 8,355,840
constexpr size_t IDX_OFF = 16711680;        // B*N*K ints = 655,360
constexpr size_t Z2_OFF  = 17367040;        // 4,128,768
constexpr size_t Z3_OFF  = 21495808;        // B*3*3*N = 294,912
constexpr size_t ACC_OFF = 21790720;        // 1024
constexpr size_t XM_OFF  = 21791744;        // 1020
constexpr size_t BF_OFF  = 21792764;        // 1020
constexpr size_t BD_OFF  = 21793784;        // 1020
constexpr size_t PB_OFF  = 21794816;        // 4*128*510 = 261,120 (s9 partials)

__device__ __forceinline__ float wave_sum(float v) {
#pragma unroll
  for (int off = 32; off; off >>= 1) v += __shfl_xor(v, off, 64);
  return v;
}
__device__ __forceinline__ float wave_max(float v) {
#pragma unroll
  for (int off = 32; off; off >>= 1) v = fmaxf(v, __shfl_xor(v, off, 64));
  return v;
}
__device__ __forceinline__ uint32_t umin32(uint32_t a, uint32_t b) { return a < b ? a : b; }
__device__ __forceinline__ uint32_t umax32(uint32_t a, uint32_t b) { return a < b ? b : a; }

// ---------------- zero accumulators ----------------
__global__ __launch_bounds__(1024) void zero_acc(float* __restrict__ a) {
  a[threadIdx.x] = 0.f;
}

// ---------------- KNN: 2 queries/thread, buffered top-20 select over one segment ----------------
// key = (f32 dist bits & 0xFFFFE000) | idx(13b) -> absolute order, merge-tree associative.
__global__ __launch_bounds__(256) void knn_kernel(const float* __restrict__ pts,
                                                  uint32_t* __restrict__ knnp) {
  __shared__ float4 tile[SEGLEN];          // 16 KB
  __shared__ uint32_t buf0[BUF * 256];     // 16 KB
  __shared__ uint32_t buf1[BUF * 256];     // 16 KB
  const int tid = threadIdx.x;
  const int n0 = blockIdx.x * 512 + tid;
  const int n1 = n0 + 256;
  const int b = blockIdx.y;
  const int s = blockIdx.z;
  const float* pb = pts + (size_t)b * Nn * 3;

  for (int i = tid; i < SEGLEN; i += 256) {
    const float* p = pb + (size_t)(s * SEGLEN + i) * 3;
    tile[i] = make_float4(p[0], p[1], p[2], 0.f);
  }
  const float q0x = pb[n0 * 3 + 0], q0y = pb[n0 * 3 + 1], q0z = pb[n0 * 3 + 2];
  const float q1x = pb[n1 * 3 + 0], q1y = pb[n1 * 3 + 1], q1z = pb[n1 * 3 + 2];
  __syncthreads();

  uint32_t keys0[KK], keys1[KK];
#pragma unroll
  for (int j = 0; j < KK; ++j) { keys0[j] = 0xFFFFFFFFu; keys1[j] = 0xFFFFFFFFu; }

  const int base = s * SEGLEN;

  // ---- warm-up: first 64 candidates, direct min/max-chain insert ----
#pragma unroll 2
  for (int j = 0; j < 64; ++j) {
    const float4 c = tile[j];
    const uint32_t tag = (uint32_t)(base + j);
    {
      const float dx = q0x - c.x, dy = q0y - c.y, dz = q0z - c.z;
      const float d2 = dx * dx + dy * dy + dz * dz;
      uint32_t mx = (__float_as_uint(d2) & 0xFFFFE000u) | tag;
#pragma unroll
      for (int q = 0; q < KK; ++q) {
        const uint32_t mn = umin32(keys0[q], mx);
        mx = umax32(keys0[q], mx);
        keys0[q] = mn;
      }
    }
    {
      const float dx = q1x - c.x, dy = q1y - c.y, dz = q1z - c.z;
      const float d2 = dx * dx + dy * dy + dz * dz;
      uint32_t mx = (__float_as_uint(d2) & 0xFFFFE000u) | tag;
#pragma unroll
      for (int q = 0; q < KK; ++q) {
        const uint32_t mn = umin32(keys1[q], mx);
        mx = umax32(keys1[q], mx);
        keys1[q] = mn;
      }
    }
  }

  uint32_t th0 = keys0[KK - 1], th1 = keys1[KK - 1];
  int cnt0 = 0, cnt1 = 0;

  // ---- main loop: screen against thresh, buffer survivors, merge rarely ----
  for (int j0 = 64; j0 < SEGLEN; j0 += 4) {
#pragma unroll
    for (int u = 0; u < 4; ++u) {
      const int j = j0 + u;
      const float4 c = tile[j];
      const uint32_t tag = (uint32_t)(base + j);
      const float dx0 = q0x - c.x, dy0 = q0y - c.y, dz0 = q0z - c.z;
      const float d20 = dx0 * dx0 + dy0 * dy0 + dz0 * dz0;
      const uint32_t key0 = (__float_as_uint(d20) & 0xFFFFE000u) | tag;
      if (key0 < th0) { buf0[cnt0 * 256 + tid] = key0; ++cnt0; }
      const float dx1 = q1x - c.x, dy1 = q1y - c.y, dz1 = q1z - c.z;
      const float d21 = dx1 * dx1 + dy1 * dy1 + dz1 * dz1;
      const uint32_t key1 = (__float_as_uint(d21) & 0xFFFFE000u) | tag;
      if (key1 < th1) { buf1[cnt1 * 256 + tid] = key1; ++cnt1; }
    }
    if (__any((cnt0 > BUF - 4) || (cnt1 > BUF - 4))) {
#pragma unroll
      for (int i = 0; i < BUF; ++i) {
        uint32_t mx0 = (i < cnt0) ? buf0[i * 256 + tid] : 0xFFFFFFFFu;
        uint32_t mx1 = (i < cnt1) ? buf1[i * 256 + tid] : 0xFFFFFFFFu;
#pragma unroll
        for (int q = 0; q < KK; ++q) {
          const uint32_t mn0 = umin32(keys0[q], mx0);
          mx0 = umax32(keys0[q], mx0);
          keys0[q] = mn0;
          const uint32_t mn1 = umin32(keys1[q], mx1);
          mx1 = umax32(keys1[q], mx1);
          keys1[q] = mn1;
        }
      }
      cnt0 = 0; cnt1 = 0;
      th0 = keys0[KK - 1]; th1 = keys1[KK - 1];
    }
  }
  // ---- final flush ----
#pragma unroll
  for (int i = 0; i < BUF; ++i) {
    uint32_t mx0 = (i < cnt0) ? buf0[i * 256 + tid] : 0xFFFFFFFFu;
    uint32_t mx1 = (i < cnt1) ? buf1[i * 256 + tid] : 0xFFFFFFFFu;
#pragma unroll
    for (int q = 0; q < KK; ++q) {
      const uint32_t mn0 = umin32(keys0[q], mx0);
      mx0 = umax32(keys0[q], mx0);
      keys0[q] = mn0;
      const uint32_t mn1 = umin32(keys1[q], mx1);
      mx1 = umax32(keys1[q], mx1);
      keys1[q] = mn1;
    }
  }

  // list-major layout: [(b*SEG+s)][j][n] -> coalesced stores per j
  uint32_t* op0 = knnp + ((size_t)(b * SEG + s) * KK) * Nn + n0;
  uint32_t* op1 = knnp + ((size_t)(b * SEG + s) * KK) * Nn + n1;
#pragma unroll
  for (int j = 0; j < KK; ++j) { op0[(size_t)j * Nn] = keys0[j]; op1[(size_t)j * Nn] = keys1[j]; }
}

// ---------------- merge tree passes ----------------
template <int LIN>
__global__ __launch_bounds__(256) void merge_pass(const uint32_t* __restrict__ in,
                                                  uint32_t* __restrict__ out) {
  constexpr int LOUT = LIN / 2;
  const int t = blockIdx.x * 256 + threadIdx.x;  // B*N*LOUT threads
  const int n = t & (Nn - 1);
  const int r = t >> 13;
  const int j = r % LOUT, b = r / LOUT;
  const uint32_t* p0 = in + ((size_t)(b * LIN + 2 * j) * KK) * Nn + n;
  const uint32_t* p1 = in + ((size_t)(b * LIN + 2 * j + 1) * KK) * Nn + n;
  uint32_t* op = out + ((size_t)(b * LOUT + j) * KK) * Nn + n;
  int i0 = 0, i1 = 0;
  uint32_t k0 = p0[0], k1 = p1[0];
#pragma unroll
  for (int m = 0; m < KK; ++m) {
    uint32_t k;
    if (k0 <= k1) { k = k0; ++i0; k0 = (i0 < KK) ? p0[(size_t)i0 * Nn] : 0xFFFFFFFFu; }
    else          { k = k1; ++i1; k1 = (i1 < KK) ? p1[(size_t)i1 * Nn] : 0xFFFFFFFFu; }
    op[(size_t)m * Nn] = k;
  }
}

__global__ __launch_bounds__(256) void merge_final(const uint32_t* __restrict__ in,
                                                   int* __restrict__ idx) {
  const int t = blockIdx.x * 256 + threadIdx.x;  // B*N threads
  const int n = t & (Nn - 1), b = t >> 13;
  const uint32_t* p0 = in + ((size_t)(b * 2 + 0) * KK) * Nn + n;
  const uint32_t* p1 = in + ((size_t)(b * 2 + 1) * KK) * Nn + n;
  int* op = idx + (size_t)t * KK;
  int i0 = 0, i1 = 0;
  uint32_t k0 = p0[0], k1 = p1[0];
#pragma unroll
  for (int m = 0; m < KK; ++m) {
    uint32_t k;
    if (k0 <= k1) { k = k0; ++i0; k0 = (i0 < KK) ? p0[(size_t)i0 * Nn] : 0xFFFFFFFFu; }
    else          { k = k1; ++i1; k1 = (i1 < KK) ? p1[(size_t)i1 * Nn] : 0xFFFFFFFFu; }
    op[m] = (int)(k & 8191u);
  }
}

// ---------------- stage 1: feature-cross + LLR(21) ----------------
__global__ __launch_bounds__(256) void s1_stats(const float* __restrict__ pts,
                                                const int* __restrict__ idx,
                                                const float* __restrict__ wf,
                                                float* __restrict__ acc) {
  __shared__ float lacc[42];
  const int tid = threadIdx.x;
  for (int i = tid; i < 42; i += 256) lacc[i] = 0.f;
  __syncthreads();
  const int t = blockIdx.x * 256 + tid;  // 0..B*N*K-1
  const int site = t / KK;
  const int n = site & (Nn - 1), b = site >> 13;
  const int m = idx[t];
  const float* pb = pts + (size_t)b * Nn * 3;
  const float ax = pb[m * 3 + 0], ay = pb[m * 3 + 1], az = pb[m * 3 + 2];
  const float cx = pb[n * 3 + 0], cy = pb[n * 3 + 1], cz = pb[n * 3 + 2];
  const float e0x = ax - cx, e0y = ay - cy, e0z = az - cz;
  const float e2x = ay * cz - az * cy, e2y = az * cx - ax * cz, e2z = ax * cy - ay * cx;
#pragma unroll
  for (int o = 0; o < 21; ++o) {
    const float w0 = wf[o * 3 + 0], w1 = wf[o * 3 + 1], w2 = wf[o * 3 + 2];
    const float px = w0 * e0x + w1 * cx + w2 * e2x;
    const float py = w0 * e0y + w1 * cy + w2 * e2y;
    const float pz = w0 * e0z + w1 * cz + w2 * e2z;
    const float nrm = sqrtf(px * px + py * py + pz * pz) + EPSF;
    const float s1 = wave_sum(nrm);
    const float s2 = wave_sum(nrm * nrm);
    if ((tid & 63) == 0) { atomicAdd(&lacc[o], s1); atomicAdd(&lacc[21 + o], s2); }
  }
  __syncthreads();
  for (int i = tid; i < 42; i += 256) atomicAdd(&acc[i], lacc[i]);
}

// single pass over all 21 output channels; gathers each neighbor once
__global__ __launch_bounds__(256) void s1_apply(const float* __restrict__ pts,
                                                const int* __restrict__ idx,
                                                const float* __restrict__ wf,
                                                const float* __restrict__ wd,
                                                const float* __restrict__ acc,
                                                float* __restrict__ x1) {
  const int t = blockIdx.x * 256 + threadIdx.x;  // site 0..B*N-1
  const int n = t & (Nn - 1), b = t >> 13;
  const float* pb = pts + (size_t)b * Nn * 3;
  const float cx = pb[n * 3 + 0], cy = pb[n * 3 + 1], cz = pb[n * 3 + 2];
  const float inv_cnt = 1.f / (float)(Bb * Nn * KK);
  float accu[21][3];
#pragma unroll
  for (int j = 0; j < 21; ++j) { accu[j][0] = 0.f; accu[j][1] = 0.f; accu[j][2] = 0.f; }
  for (int k = 0; k < KK; ++k) {
    const int m = idx[(size_t)t * KK + k];
    const float ax = pb[m * 3 + 0], ay = pb[m * 3 + 1], az = pb[m * 3 + 2];
    const float e0x = ax - cx, e0y = ay - cy, e0z = az - cz;
    const float e2x = ay * cz - az * cy, e2y = az * cx - ax * cz, e2z = ax * cy - ay * cx;
#pragma unroll
    for (int o = 0; o < 21; ++o) {
      const float wf0 = wf[o * 3 + 0], wf1 = wf[o * 3 + 1], wf2 = wf[o * 3 + 2];
      const float px = wf0 * e0x + wf1 * cx + wf2 * e2x;
      const float py = wf0 * e0y + wf1 * cy + wf2 * e2y;
      const float pz = wf0 * e0z + wf1 * cz + wf2 * e2z;
      const float nrm = sqrtf(px * px + py * py + pz * pz) + EPSF;
      const float mn = acc[o] * inv_cnt;
      const float vr = acc[21 + o] * inv_cnt - mn * mn;
      const float factor = (nrm - mn) * rsqrtf(vr + BN_EPSF) / nrm;
      const float q0 = px * factor, q1 = py * factor, q2 = pz * factor;
      const float wd0 = wd[o * 3 + 0], wd1 = wd[o * 3 + 1], wd2 = wd[o * 3 + 2];
      const float dx = wd0 * e0x + wd1 * cx + wd2 * e2x;
      const float dy = wd0 * e0y + wd1 * cy + wd2 * e2y;
      const float dz = wd0 * e0z + wd1 * cz + wd2 * e2z;
      const float dot = q0 * dx + q1 * dy + q2 * dz;
      const float dsq = dx * dx + dy * dy + dz * dz;
      const float corr = (dot < 0.f) ? dot / (dsq + EPSF) : 0.f;
      accu[o][0] += q0 - corr * dx;
      accu[o][1] += q1 - corr * dy;
      accu[o][2] += q2 - corr * dz;
    }
  }
  const float sc = 1.f / (float)KK;
  float* ob = x1 + (size_t)b * 21 * 3 * Nn + n;
#pragma unroll
  for (int o = 0; o < 21; ++o) {
    ob[(o * 3 + 0) * Nn] = accu[o][0] * sc;
    ob[(o * 3 + 1) * Nn] = accu[o][1] * sc;
    ob[(o * 3 + 2) * Nn] = accu[o][2] * sc;
  }
}

// ---------------- generic VN layer: stats + apply (o-tile = blockIdx.y) ----------------
template <int CIN, int COUT, int OT, bool HAS_BIAS>
__global__ __launch_bounds__(256) void vn_stats(const float* __restrict__ X,
                                                const float* __restrict__ Wf, int ws,
                                                const float* __restrict__ biasF,
                                                float* __restrict__ acc) {
  __shared__ float lacc[2 * OT];
  const int tid = threadIdx.x;
  if (tid < 2 * OT) lacc[tid] = 0.f;
  __syncthreads();
  const int o0 = blockIdx.y * OT;
  const int t = blockIdx.x * 256 + tid;
  const int n = t & (Nn - 1), b = t >> 13;
  const float* xb = X + (size_t)b * CIN * 3 * Nn + n;
  float p[OT][3];
#pragma unroll
  for (int j = 0; j < OT; ++j)
#pragma unroll
    for (int dd = 0; dd < 3; ++dd)
      p[j][dd] = HAS_BIAS ? biasF[((size_t)b * COUT + o0 + j) * 3 + dd] : 0.f;
  for (int c = 0; c < CIN; ++c) {
    const float x0 = xb[(c * 3 + 0) * Nn];
    const float x1v = xb[(c * 3 + 1) * Nn];
    const float x2v = xb[(c * 3 + 2) * Nn];
#pragma unroll
    for (int j = 0; j < OT; ++j) {
      const float wv = Wf[(o0 + j) * ws + c];
      p[j][0] += wv * x0; p[j][1] += wv * x1v; p[j][2] += wv * x2v;
    }
  }
#pragma unroll
  for (int j = 0; j < OT; ++j) {
    const float nrm = sqrtf(p[j][0] * p[j][0] + p[j][1] * p[j][1] + p[j][2] * p[j][2]) + EPSF;
    const float s1 = wave_sum(nrm);
    const float s2 = wave_sum(nrm * nrm);
    if ((tid & 63) == 0) { atomicAdd(&lacc[j], s1); atomicAdd(&lacc[OT + j], s2); }
  }
  __syncthreads();
  if (tid < 2 * OT) {
    const int g = (tid < OT) ? (o0 + tid) : (COUT + o0 + (tid - OT));
    atomicAdd(&acc[g], lacc[tid]);
  }
}

template <int CIN, int COUT, int OT, bool HAS_BIAS, bool DO_LLR>
__global__ __launch_bounds__(256) void vn_apply(const float* __restrict__ X,
                                                const float* __restrict__ Wf,
                                                const float* __restrict__ Wd, int ws,
                                                const float* __restrict__ biasF,
                                                const float* __restrict__ biasD,
                                                const float* __restrict__ acc, float cntinv,
                                                float* __restrict__ OUT) {
  const int o0 = blockIdx.y * OT;
  const int t = blockIdx.x * 256 + threadIdx.x;
  const int n = t & (Nn - 1), b = t >> 13;
  const float* xb = X + (size_t)b * CIN * 3 * Nn + n;
  float* ob = OUT + (size_t)b * COUT * 3 * Nn + n;
  float p[OT][3], dv[OT][3];
#pragma unroll
  for (int j = 0; j < OT; ++j)
#pragma unroll
    for (int dd = 0; dd < 3; ++dd) {
      p[j][dd] = HAS_BIAS ? biasF[((size_t)b * COUT + o0 + j) * 3 + dd] : 0.f;
      if constexpr (DO_LLR)
        dv[j][dd] = HAS_BIAS ? biasD[((size_t)b * COUT + o0 + j) * 3 + dd] : 0.f;
      else
        dv[j][dd] = 0.f;
    }
  for (int c = 0; c < CIN; ++c) {
    const float x0 = xb[(c * 3 + 0) * Nn];
    const float x1v = xb[(c * 3 + 1) * Nn];
    const float x2v = xb[(c * 3 + 2) * Nn];
#pragma unroll
    for (int j = 0; j < OT; ++j) {
      const float wfv = Wf[(o0 + j) * ws + c];
      p[j][0] += wfv * x0; p[j][1] += wfv * x1v; p[j][2] += wfv * x2v;
      if constexpr (DO_LLR) {
        const float wdv = Wd[(o0 + j) * ws + c];
        dv[j][0] += wdv * x0; dv[j][1] += wdv * x1v; dv[j][2] += wdv * x2v;
      }
    }
  }
#pragma unroll
  for (int j = 0; j < OT; ++j) {
    const int o = o0 + j;
    const float nrm = sqrtf(p[j][0] * p[j][0] + p[j][1] * p[j][1] + p[j][2] * p[j][2]) + EPSF;
    const float mn = acc[o] * cntinv;
    const float vr = acc[COUT + o] * cntinv - mn * mn;
    const float factor = (nrm - mn) * rsqrtf(vr + BN_EPSF) / nrm;
    float r0 = p[j][0] * factor, r1 = p[j][1] * factor, r2 = p[j][2] * factor;
    if constexpr (DO_LLR) {
      const float dot = r0 * dv[j][0] + r1 * dv[j][1] + r2 * dv[j][2];
      const float dsq = dv[j][0] * dv[j][0] + dv[j][1] * dv[j][1] + dv[j][2] * dv[j][2];
      const float corr = (dot < 0.f) ? dot / (dsq + EPSF) : 0.f;
      r0 -= corr * dv[j][0]; r1 -= corr * dv[j][1]; r2 -= corr * dv[j][2];
    }
    ob[(o * 3 + 0) * Nn] = r0;
    ob[(o * 3 + 1) * Nn] = r1;
    ob[(o * 3 + 2) * Nn] = r2;
  }
}

// ---------------- stage 5: mean over N, bias precompute, small outputs ----------------
__global__ __launch_bounds__(256) void s5_mean(const float* __restrict__ x4,
                                               float* __restrict__ xm,
                                               float* __restrict__ out) {
  const int row = blockIdx.x;  // 0..1019 = b*255 + c*3 + dd
  const int b = row / 255, rcd = row % 255;
  const float* src = x4 + (size_t)b * 255 * Nn + (size_t)rcd * Nn;
  float s = 0.f;
  for (int n = threadIdx.x; n < Nn; n += 256) s += src[n];
  s = wave_sum(s);
  __shared__ float wsum[4];
  if ((threadIdx.x & 63) == 0) wsum[threadIdx.x >> 6] = s;
  __syncthreads();
  if (threadIdx.x == 0) {
    const float mv = (wsum[0] + wsum[1] + wsum[2] + wsum[3]) * (1.f / (float)Nn);
    xm[row] = mv;
    out[2040 + row] = mv;  // x_mean_out
  }
}

__global__ __launch_bounds__(256) void s5_bias(const float* __restrict__ xm,
                                               const float* __restrict__ ws1f,
                                               const float* __restrict__ ws1d,
                                               float* __restrict__ biasF,
                                               float* __restrict__ biasD,
                                               float* __restrict__ out) {
  const int t = blockIdx.x * 256 + threadIdx.x;
  if (t < 1020) {
    const int b = t / 255, r = t % 255, o = r / 3, dd = r % 3;
    float sf = 0.f, sd = 0.f;
    for (int c = 0; c < 85; ++c) {
      const float xv = xm[(b * 85 + c) * 3 + dd];
      sf += ws1f[o * 170 + 85 + c] * xv;
      sd += ws1d[o * 170 + 85 + c] * xv;
    }
    biasF[t] = sf;
    biasD[t] = sd;
  }
  if (t < 340) {
    const int b = t / 85, c = t % 85;
    out[3060 + t] = (xm[(b * 85 + c) * 3 + 0] + xm[(b * 85 + c) * 3 + 1] +
                     xm[(b * 85 + c) * 3 + 2]) * (1.f / 3.f);  // center_loc
  }
}

// ---------------- stage 8: z3 = wlin · z2 ----------------
__global__ __launch_bounds__(256) void s8_z3(const float* __restrict__ z2,
                                             const float* __restrict__ wlin,
                                             float* __restrict__ z3) {
  const int t = blockIdx.x * 256 + threadIdx.x;
  const int n = t & (Nn - 1), b = t >> 13;
  const float* zb = z2 + (size_t)b * 42 * 3 * Nn + n;
  float accv[3][3];
#pragma unroll
  for (int o = 0; o < 3; ++o)
#pragma unroll
    for (int dd = 0; dd < 3; ++dd) accv[o][dd] = 0.f;
  for (int c = 0; c < 42; ++c) {
    const float x0 = zb[(c * 3 + 0) * Nn];
    const float x1v = zb[(c * 3 + 1) * Nn];
    const float x2v = zb[(c * 3 + 2) * Nn];
#pragma unroll
    for (int o = 0; o < 3; ++o) {
      const float wv = wlin[o * 42 + c];
      accv[o][0] += wv * x0; accv[o][1] += wv * x1v; accv[o][2] += wv * x2v;
    }
  }
  float* ob = z3 + (size_t)b * 9 * Nn + n;
#pragma unroll
  for (int o = 0; o < 3; ++o)
#pragma unroll
    for (int dd = 0; dd < 3; ++dd) ob[(o * 3 + dd) * Nn] = accv[o][dd];
}

// ---------------- stage 9: x_std + max over N (single read of x4/z3) ----------------
__global__ __launch_bounds__(256) void s9_partial(const float* __restrict__ x4,
                                                  const float* __restrict__ xm,
                                                  const float* __restrict__ z3,
                                                  float* __restrict__ pbuf) {
  const int tid = threadIdx.x;
  const int n = blockIdx.x * 256 + tid;  // chunk of 256 n's
  const int b = blockIdx.y;
  const int w = tid >> 6;
  const float* zb = z3 + (size_t)b * 9 * Nn + n;
  float zk[3][3];
#pragma unroll
  for (int k = 0; k < 3; ++k)
#pragma unroll
    for (int j = 0; j < 3; ++j) zk[k][j] = zb[(k * 3 + j) * Nn];
  const float* xb = x4 + (size_t)b * 255 * Nn + n;
  float* pbw = pbuf + ((size_t)(b * 32 + blockIdx.x) * 4 + w) * 510;
  for (int i = 0; i < 170; ++i) {
    float xj0, xj1, xj2;
    if (i < 85) {
      xj0 = xb[(i * 3 + 0) * Nn];
      xj1 = xb[(i * 3 + 1) * Nn];
      xj2 = xb[(i * 3 + 2) * Nn];
    } else {
      xj0 = xm[(b * 85 + (i - 85)) * 3 + 0];
      xj1 = xm[(b * 85 + (i - 85)) * 3 + 1];
      xj2 = xm[(b * 85 + (i - 85)) * 3 + 2];
    }
#pragma unroll
    for (int k = 0; k < 3; ++k) {
      float v = xj0 * zk[k][0] + xj1 * zk[k][1] + xj2 * zk[k][2];
      v = wave_max(v);
      if ((tid & 63) == 0) pbw[i * 3 + k] = v;
    }
  }
}

__global__ __launch_bounds__(512) void s9_reduce(const float* __restrict__ pbuf,
                                                 float* __restrict__ out) {
  const int b = blockIdx.x;
  const int r = threadIdx.x;
  if (r < 510) {
    float m = -3.402823466e38f;
    for (int c = 0; c < 128; ++c) m = fmaxf(m, pbuf[((size_t)(b * 128 + c)) * 510 + r]);
    out[b * 510 + r] = m;
  }
}

// ---------------- launch ----------------
extern "C" void kernel_launch(void* const* d_in, const int* in_sizes, int n_in,
                              void* d_out, int out_size, void* d_ws, size_t ws_size,
                              hipStream_t stream) {
  const float* pts   = (const float*)d_in[0];
  const float* wposf = (const float*)d_in[1];
  const float* wposd = (const float*)d_in[2];
  const float* w1f   = (const float*)d_in[3];
  const float* w1d   = (const float*)d_in[4];
  const float* w2f   = (const float*)d_in[5];
  const float* w2d   = (const float*)d_in[6];
  const float* w3    = (const float*)d_in[7];
  const float* ws1f  = (const float*)d_in[8];
  const float* ws1d  = (const float*)d_in[9];
  const float* ws2f  = (const float*)d_in[10];
  const float* ws2d  = (const float*)d_in[11];
  const float* wlin  = (const float*)d_in[12];
  float* out = (float*)d_out;
  float* wsf = (float*)d_ws;

  uint32_t* knnp0 = (uint32_t*)(wsf + KNN0_OFF);
  uint32_t* knnp1 = (uint32_t*)(wsf + KNN1_OFF);
  float* x1 = wsf + X1_OFF;
  float* x2 = wsf + X2_OFF;
  float* x3 = wsf + X3_OFF;
  float* z1 = wsf + Z1_OFF;
  float* x4 = wsf + X4_OFF;
  int* idx  = (int*)(wsf + IDX_OFF);
  float* z2 = wsf + Z2_OFF;
  float* z3 = wsf + Z3_OFF;
  float* acc = wsf + ACC_OFF;
  float* xm = wsf + XM_OFF;
  float* biasF = wsf + BF_OFF;
  float* biasD = wsf + BD_OFF;
  float* pbuf = wsf + PB_OFF;

  const float inv_sites = 1.f / (float)(Bb * Nn);

  zero_acc<<<1, 1024, 0, stream>>>(acc);
  knn_kernel<<<dim3(Nn / 512, Bb, SEG), 256, 0, stream>>>(pts, knnp0);
  merge_pass<8><<<Bb * Nn * 4 / 256, 256, 0, stream>>>(knnp0, knnp1);
  merge_pass<4><<<Bb * Nn * 2 / 256, 256, 0, stream>>>(knnp1, knnp0);
  merge_final<<<Bb * Nn / 256, 256, 0, stream>>>(knnp0, idx);

  s1_stats<<<Bb * Nn * KK / 256, 256, 0, stream>>>(pts, idx, wposf, acc + 0);
  s1_apply<<<Bb * Nn / 256, 256, 0, stream>>>(pts, idx, wposf, wposd, acc + 0, x1);

  vn_stats<21, 21, 7, false><<<dim3(Bb * Nn / 256, 3), 256, 0, stream>>>(x1, w1f, 21, nullptr, acc + 64);
  vn_apply<21, 21, 7, false, true><<<dim3(Bb * Nn / 256, 3), 256, 0, stream>>>(
      x1, w1f, w1d, 21, nullptr, nullptr, acc + 64, inv_sites, x2);

  vn_stats<21, 42, 7, false><<<dim3(Bb * Nn / 256, 6), 256, 0, stream>>>(x2, w2f, 42, nullptr, acc + 128);
  vn_apply<21, 42, 7, false, true><<<dim3(Bb * Nn / 256, 6), 256, 0, stream>>>(
      x2, w2f, w2d, 42, nullptr, nullptr, acc + 128, inv_sites, x3);

  vn_stats<42, 85, 17, false><<<dim3(Bb * Nn / 256, 5), 256, 0, stream>>>(x3, w3, 42, nullptr, acc + 256);
  vn_apply<42, 85, 17, false, false><<<dim3(Bb * Nn / 256, 5), 256, 0, stream>>>(
      x3, w3, w3, 42, nullptr, nullptr, acc + 256, inv_sites, x4);

  s5_mean<<<Bb * 255, 256, 0, stream>>>(x4, xm, out);
  s5_bias<<<4, 256, 0, stream>>>(xm, ws1f, ws1d, biasF, biasD, out);

  vn_stats<85, 85, 17, true><<<dim3(Bb * Nn / 256, 5), 256, 0, stream>>>(x4, ws1f, 170, biasF, acc + 512);
  vn_apply<85, 85, 17, true, true><<<dim3(Bb * Nn / 256, 5), 256, 0, stream>>>(
      x4, ws1f, ws1d, 170, biasF, biasD, acc + 512, inv_sites, z1);

  vn_stats<85, 42, 14, false><<<dim3(Bb * Nn / 256, 3), 256, 0, stream>>>(z1, ws2f, 85, nullptr, acc + 768);
  vn_apply<85, 42, 14, false, true><<<dim3(Bb * Nn / 256, 3), 256, 0, stream>>>(
      z1, ws2f, ws2d, 85, nullptr, nullptr, acc + 768, inv_sites, z2);

  s8_z3<<<Bb * Nn / 256, 256, 0, stream>>>(z2, wlin, z3);
  s9_partial<<<dim3(32, Bb), 256, 0, stream>>>(x4, xm, z3, pbuf);
  s9_reduce<<<Bb, 512, 0, stream>>>(pbuf, out);
}

// Round 6
// 969.093 us; speedup vs baseline: 1.2357x; 1.1974x over previous
//
#include <hip/hip_runtime.h>
#include <cstdint>
#include <cstddef>

#define EPSF 1e-6f
#define BN_EPSF 1e-5f

constexpr int Bb = 4;
constexpr int Nn = 8192;
constexpr int KK = 20;
constexpr int SEG = 8;            // knn candidate segments
constexpr int SEGLEN = Nn / SEG;  // 1024
constexpr int BUF = 8;            // per-lane candidate buffer (LDS slots, per query)

// ---------------- workspace layout (float elements) ----------------
constexpr size_t KNN0_OFF = 0;              // B*8*N*20 u32 = 5,242,880
constexpr size_t KNN1_OFF = 5242880;        // B*4*N*20 u32 = 2,621,440 (ends 7,864,320)
constexpr size_t X1_OFF  = 0;               // B*21*3*N = 2,064,384
constexpr size_t X2_OFF  = 2064384;
constexpr size_t X3_OFF  = 4128768;         // B*42*3*N = 4,128,768 (ends 8,257,536)
constexpr size_t Z1_OFF  = 0;               // B*85*3*N = 8,355,840
constexpr size_t X4_OFF  = 8355840;         // 8,355,840
constexpr size_t IDX_OFF = 16711680;        // B*N*K ints = 655,360
constexpr size_t Z2_OFF  = 17367040;        // 4,128,768
constexpr size_t Z3_OFF  = 21495808;        // B*3*3*N = 294,912
constexpr size_t ACC_OFF = 21790720;        // 1024
constexpr size_t XM_OFF  = 21791744;        // 1020
constexpr size_t BF_OFF  = 21792764;        // 1020
constexpr size_t BD_OFF  = 21793784;        // 1020

__device__ __forceinline__ float wave_sum(float v) {
#pragma unroll
  for (int off = 32; off; off >>= 1) v += __shfl_xor(v, off, 64);
  return v;
}
__device__ __forceinline__ float wave_max(float v) {
#pragma unroll
  for (int off = 32; off; off >>= 1) v = fmaxf(v, __shfl_xor(v, off, 64));
  return v;
}
__device__ __forceinline__ uint32_t umin32(uint32_t a, uint32_t b) { return a < b ? a : b; }
__device__ __forceinline__ uint32_t umax32(uint32_t a, uint32_t b) { return a < b ? b : a; }

// ---------------- zero accumulators ----------------
__global__ __launch_bounds__(1024) void zero_acc(float* __restrict__ a) {
  a[threadIdx.x] = 0.f;
}

// ---------------- KNN: 2 queries/thread (128 thr), buffered top-20 over one segment ----------------
// key = (f32 dist bits & 0xFFFFE000) | idx(13b) -> absolute order, merge-tree associative.
__global__ __launch_bounds__(128) void knn_kernel(const float* __restrict__ pts,
                                                  uint32_t* __restrict__ knnp) {
  __shared__ float4 tile[SEGLEN];          // 16 KB
  __shared__ uint32_t buf0[BUF * 128];     // 4 KB
  __shared__ uint32_t buf1[BUF * 128];     // 4 KB  -> total 24 KB/block
  const int tid = threadIdx.x;
  const int n0 = blockIdx.x * 256 + tid;
  const int n1 = n0 + 128;
  const int b = blockIdx.y;
  const int s = blockIdx.z;
  const float* pb = pts + (size_t)b * Nn * 3;

  for (int i = tid; i < SEGLEN; i += 128) {
    const float* p = pb + (size_t)(s * SEGLEN + i) * 3;
    tile[i] = make_float4(p[0], p[1], p[2], 0.f);
  }
  const float q0x = pb[n0 * 3 + 0], q0y = pb[n0 * 3 + 1], q0z = pb[n0 * 3 + 2];
  const float q1x = pb[n1 * 3 + 0], q1y = pb[n1 * 3 + 1], q1z = pb[n1 * 3 + 2];
  __syncthreads();

  uint32_t keys0[KK], keys1[KK];
#pragma unroll
  for (int j = 0; j < KK; ++j) { keys0[j] = 0xFFFFFFFFu; keys1[j] = 0xFFFFFFFFu; }

  const int base = s * SEGLEN;

  // ---- warm-up: first 32 candidates, direct min/max-chain insert ----
#pragma unroll 2
  for (int j = 0; j < 32; ++j) {
    const float4 c = tile[j];
    const uint32_t tag = (uint32_t)(base + j);
    {
      const float dx = q0x - c.x, dy = q0y - c.y, dz = q0z - c.z;
      const float d2 = dx * dx + dy * dy + dz * dz;
      uint32_t mx = (__float_as_uint(d2) & 0xFFFFE000u) | tag;
#pragma unroll
      for (int q = 0; q < KK; ++q) {
        const uint32_t mn = umin32(keys0[q], mx);
        mx = umax32(keys0[q], mx);
        keys0[q] = mn;
      }
    }
    {
      const float dx = q1x - c.x, dy = q1y - c.y, dz = q1z - c.z;
      const float d2 = dx * dx + dy * dy + dz * dz;
      uint32_t mx = (__float_as_uint(d2) & 0xFFFFE000u) | tag;
#pragma unroll
      for (int q = 0; q < KK; ++q) {
        const uint32_t mn = umin32(keys1[q], mx);
        mx = umax32(keys1[q], mx);
        keys1[q] = mn;
      }
    }
  }

  uint32_t th0 = keys0[KK - 1], th1 = keys1[KK - 1];
  int cnt0 = 0, cnt1 = 0;

  // ---- main loop: screen against thresh, buffer survivors, merge rarely ----
  for (int j0 = 32; j0 < SEGLEN; j0 += 4) {
#pragma unroll
    for (int u = 0; u < 4; ++u) {
      const int j = j0 + u;
      const float4 c = tile[j];
      const uint32_t tag = (uint32_t)(base + j);
      const float dx0 = q0x - c.x, dy0 = q0y - c.y, dz0 = q0z - c.z;
      const float d20 = dx0 * dx0 + dy0 * dy0 + dz0 * dz0;
      const uint32_t key0 = (__float_as_uint(d20) & 0xFFFFE000u) | tag;
      if (key0 < th0) { buf0[cnt0 * 128 + tid] = key0; ++cnt0; }
      const float dx1 = q1x - c.x, dy1 = q1y - c.y, dz1 = q1z - c.z;
      const float d21 = dx1 * dx1 + dy1 * dy1 + dz1 * dz1;
      const uint32_t key1 = (__float_as_uint(d21) & 0xFFFFE000u) | tag;
      if (key1 < th1) { buf1[cnt1 * 128 + tid] = key1; ++cnt1; }
    }
    if (__any((cnt0 > BUF - 4) || (cnt1 > BUF - 4))) {
#pragma unroll
      for (int i = 0; i < BUF; ++i) {
        uint32_t mx0 = (i < cnt0) ? buf0[i * 128 + tid] : 0xFFFFFFFFu;
        uint32_t mx1 = (i < cnt1) ? buf1[i * 128 + tid] : 0xFFFFFFFFu;
#pragma unroll
        for (int q = 0; q < KK; ++q) {
          const uint32_t mn0 = umin32(keys0[q], mx0);
          mx0 = umax32(keys0[q], mx0);
          keys0[q] = mn0;
          const uint32_t mn1 = umin32(keys1[q], mx1);
          mx1 = umax32(keys1[q], mx1);
          keys1[q] = mn1;
        }
      }
      cnt0 = 0; cnt1 = 0;
      th0 = keys0[KK - 1]; th1 = keys1[KK - 1];
    }
  }
  // ---- final flush ----
#pragma unroll
  for (int i = 0; i < BUF; ++i) {
    uint32_t mx0 = (i < cnt0) ? buf0[i * 128 + tid] : 0xFFFFFFFFu;
    uint32_t mx1 = (i < cnt1) ? buf1[i * 128 + tid] : 0xFFFFFFFFu;
#pragma unroll
    for (int q = 0; q < KK; ++q) {
      const uint32_t mn0 = umin32(keys0[q], mx0);
      mx0 = umax32(keys0[q], mx0);
      keys0[q] = mn0;
      const uint32_t mn1 = umin32(keys1[q], mx1);
      mx1 = umax32(keys1[q], mx1);
      keys1[q] = mn1;
    }
  }

  // list-major layout: [(b*SEG+s)][j][n] -> coalesced stores per j
  uint32_t* op0 = knnp + ((size_t)(b * SEG + s) * KK) * Nn + n0;
  uint32_t* op1 = knnp + ((size_t)(b * SEG + s) * KK) * Nn + n1;
#pragma unroll
  for (int j = 0; j < KK; ++j) { op0[(size_t)j * Nn] = keys0[j]; op1[(size_t)j * Nn] = keys1[j]; }
}

// ---------------- merge tree passes ----------------
template <int LIN>
__global__ __launch_bounds__(256) void merge_pass(const uint32_t* __restrict__ in,
                                                  uint32_t* __restrict__ out) {
  constexpr int LOUT = LIN / 2;
  const int t = blockIdx.x * 256 + threadIdx.x;  // B*N*LOUT threads
  const int n = t & (Nn - 1);
  const int r = t >> 13;
  const int j = r % LOUT, b = r / LOUT;
  const uint32_t* p0 = in + ((size_t)(b * LIN + 2 * j) * KK) * Nn + n;
  const uint32_t* p1 = in + ((size_t)(b * LIN + 2 * j + 1) * KK) * Nn + n;
  uint32_t* op = out + ((size_t)(b * LOUT + j) * KK) * Nn + n;
  int i0 = 0, i1 = 0;
  uint32_t k0 = p0[0], k1 = p1[0];
#pragma unroll
  for (int m = 0; m < KK; ++m) {
    uint32_t k;
    if (k0 <= k1) { k = k0; ++i0; k0 = (i0 < KK) ? p0[(size_t)i0 * Nn] : 0xFFFFFFFFu; }
    else          { k = k1; ++i1; k1 = (i1 < KK) ? p1[(size_t)i1 * Nn] : 0xFFFFFFFFu; }
    op[(size_t)m * Nn] = k;
  }
}

__global__ __launch_bounds__(256) void merge_final(const uint32_t* __restrict__ in,
                                                   int* __restrict__ idx) {
  const int t = blockIdx.x * 256 + threadIdx.x;  // B*N threads
  const int n = t & (Nn - 1), b = t >> 13;
  const uint32_t* p0 = in + ((size_t)(b * 2 + 0) * KK) * Nn + n;
  const uint32_t* p1 = in + ((size_t)(b * 2 + 1) * KK) * Nn + n;
  int* op = idx + (size_t)t * KK;
  int i0 = 0, i1 = 0;
  uint32_t k0 = p0[0], k1 = p1[0];
#pragma unroll
  for (int m = 0; m < KK; ++m) {
    uint32_t k;
    if (k0 <= k1) { k = k0; ++i0; k0 = (i0 < KK) ? p0[(size_t)i0 * Nn] : 0xFFFFFFFFu; }
    else          { k = k1; ++i1; k1 = (i1 < KK) ? p1[(size_t)i1 * Nn] : 0xFFFFFFFFu; }
    op[m] = (int)(k & 8191u);
  }
}

// ---------------- stage 1: feature-cross + LLR(21) ----------------
// 4 neighbors per thread: 4x fewer same-address atomics and wave_sum chains.
__global__ __launch_bounds__(256) void s1_stats(const float* __restrict__ pts,
                                                const int* __restrict__ idx,
                                                const float* __restrict__ wf,
                                                float* __restrict__ acc) {
  __shared__ float lacc[42];
  const int tid = threadIdx.x;
  for (int i = tid; i < 42; i += 256) lacc[i] = 0.f;
  __syncthreads();
  const int t = blockIdx.x * 256 + tid;  // 0..B*N*5-1
  const int site = t / 5;
  const int kq = (t % 5) * 4;
  const int n = site & (Nn - 1), b = site >> 13;
  const float* pb = pts + (size_t)b * Nn * 3;
  const float cx = pb[n * 3 + 0], cy = pb[n * 3 + 1], cz = pb[n * 3 + 2];
  float s1a[21], s2a[21];
#pragma unroll
  for (int o = 0; o < 21; ++o) { s1a[o] = 0.f; s2a[o] = 0.f; }
#pragma unroll
  for (int k = kq; k < kq + 4; ++k) {
    const int m = idx[(size_t)site * KK + k];
    const float ax = pb[m * 3 + 0], ay = pb[m * 3 + 1], az = pb[m * 3 + 2];
    const float e0x = ax - cx, e0y = ay - cy, e0z = az - cz;
    const float e2x = ay * cz - az * cy, e2y = az * cx - ax * cz, e2z = ax * cy - ay * cx;
#pragma unroll
    for (int o = 0; o < 21; ++o) {
      const float w0 = wf[o * 3 + 0], w1 = wf[o * 3 + 1], w2 = wf[o * 3 + 2];
      const float px = w0 * e0x + w1 * cx + w2 * e2x;
      const float py = w0 * e0y + w1 * cy + w2 * e2y;
      const float pz = w0 * e0z + w1 * cz + w2 * e2z;
      const float nrm = sqrtf(px * px + py * py + pz * pz) + EPSF;
      s1a[o] += nrm;
      s2a[o] += nrm * nrm;
    }
  }
#pragma unroll
  for (int o = 0; o < 21; ++o) {
    const float s1 = wave_sum(s1a[o]);
    const float s2 = wave_sum(s2a[o]);
    if ((tid & 63) == 0) { atomicAdd(&lacc[o], s1); atomicAdd(&lacc[21 + o], s2); }
  }
  __syncthreads();
  for (int i = tid; i < 42; i += 256) atomicAdd(&acc[i], lacc[i]);
}

// tile of 7 output channels per block (blockIdx.y)
__global__ __launch_bounds__(256) void s1_apply(const float* __restrict__ pts,
                                                const int* __restrict__ idx,
                                                const float* __restrict__ wf,
                                                const float* __restrict__ wd,
                                                const float* __restrict__ acc,
                                                float* __restrict__ x1) {
  const int t = blockIdx.x * 256 + threadIdx.x;  // site 0..B*N-1
  const int o0 = blockIdx.y * 7;
  const int n = t & (Nn - 1), b = t >> 13;
  const float* pb = pts + (size_t)b * Nn * 3;
  const float cx = pb[n * 3 + 0], cy = pb[n * 3 + 1], cz = pb[n * 3 + 2];
  const float inv_cnt = 1.f / (float)(Bb * Nn * KK);
  float meano[7], istdo[7];
#pragma unroll
  for (int j = 0; j < 7; ++j) {
    const float mn = acc[o0 + j] * inv_cnt;
    const float vr = acc[21 + o0 + j] * inv_cnt - mn * mn;
    meano[j] = mn;
    istdo[j] = rsqrtf(vr + BN_EPSF);
  }
  float accu[7][3];
#pragma unroll
  for (int j = 0; j < 7; ++j) { accu[j][0] = 0.f; accu[j][1] = 0.f; accu[j][2] = 0.f; }
  for (int k = 0; k < KK; ++k) {
    const int m = idx[(size_t)t * KK + k];
    const float ax = pb[m * 3 + 0], ay = pb[m * 3 + 1], az = pb[m * 3 + 2];
    const float e0x = ax - cx, e0y = ay - cy, e0z = az - cz;
    const float e2x = ay * cz - az * cy, e2y = az * cx - ax * cz, e2z = ax * cy - ay * cx;
#pragma unroll
    for (int j = 0; j < 7; ++j) {
      const int o = o0 + j;
      const float wf0 = wf[o * 3 + 0], wf1 = wf[o * 3 + 1], wf2 = wf[o * 3 + 2];
      const float px = wf0 * e0x + wf1 * cx + wf2 * e2x;
      const float py = wf0 * e0y + wf1 * cy + wf2 * e2y;
      const float pz = wf0 * e0z + wf1 * cz + wf2 * e2z;
      const float nrm = sqrtf(px * px + py * py + pz * pz) + EPSF;
      const float factor = (nrm - meano[j]) * istdo[j] / nrm;
      const float q0 = px * factor, q1 = py * factor, q2 = pz * factor;
      const float wd0 = wd[o * 3 + 0], wd1 = wd[o * 3 + 1], wd2 = wd[o * 3 + 2];
      const float dx = wd0 * e0x + wd1 * cx + wd2 * e2x;
      const float dy = wd0 * e0y + wd1 * cy + wd2 * e2y;
      const float dz = wd0 * e0z + wd1 * cz + wd2 * e2z;
      const float dot = q0 * dx + q1 * dy + q2 * dz;
      const float dsq = dx * dx + dy * dy + dz * dz;
      const float corr = (dot < 0.f) ? dot / (dsq + EPSF) : 0.f;
      accu[j][0] += q0 - corr * dx;
      accu[j][1] += q1 - corr * dy;
      accu[j][2] += q2 - corr * dz;
    }
  }
  const float sc = 1.f / (float)KK;
  float* ob = x1 + (size_t)b * 21 * 3 * Nn + n;
#pragma unroll
  for (int j = 0; j < 7; ++j) {
    const int o = o0 + j;
    ob[(o * 3 + 0) * Nn] = accu[j][0] * sc;
    ob[(o * 3 + 1) * Nn] = accu[j][1] * sc;
    ob[(o * 3 + 2) * Nn] = accu[j][2] * sc;
  }
}

// ---------------- generic VN layer: stats + apply (o-tile = blockIdx.y) ----------------
template <int CIN, int COUT, int OT, bool HAS_BIAS>
__global__ __launch_bounds__(256) void vn_stats(const float* __restrict__ X,
                                                const float* __restrict__ Wf, int ws,
                                                const float* __restrict__ biasF,
                                                float* __restrict__ acc) {
  __shared__ float lacc[2 * OT];
  const int tid = threadIdx.x;
  if (tid < 2 * OT) lacc[tid] = 0.f;
  __syncthreads();
  const int o0 = blockIdx.y * OT;
  const int t = blockIdx.x * 256 + tid;
  const int n = t & (Nn - 1), b = t >> 13;
  const float* xb = X + (size_t)b * CIN * 3 * Nn + n;
  float p[OT][3];
#pragma unroll
  for (int j = 0; j < OT; ++j)
#pragma unroll
    for (int dd = 0; dd < 3; ++dd)
      p[j][dd] = HAS_BIAS ? biasF[((size_t)b * COUT + o0 + j) * 3 + dd] : 0.f;
  for (int c = 0; c < CIN; ++c) {
    const float x0 = xb[(c * 3 + 0) * Nn];
    const float x1v = xb[(c * 3 + 1) * Nn];
    const float x2v = xb[(c * 3 + 2) * Nn];
#pragma unroll
    for (int j = 0; j < OT; ++j) {
      const float wv = Wf[(o0 + j) * ws + c];
      p[j][0] += wv * x0; p[j][1] += wv * x1v; p[j][2] += wv * x2v;
    }
  }
#pragma unroll
  for (int j = 0; j < OT; ++j) {
    const float nrm = sqrtf(p[j][0] * p[j][0] + p[j][1] * p[j][1] + p[j][2] * p[j][2]) + EPSF;
    const float s1 = wave_sum(nrm);
    const float s2 = wave_sum(nrm * nrm);
    if ((tid & 63) == 0) { atomicAdd(&lacc[j], s1); atomicAdd(&lacc[OT + j], s2); }
  }
  __syncthreads();
  if (tid < 2 * OT) {
    const int g = (tid < OT) ? (o0 + tid) : (COUT + o0 + (tid - OT));
    atomicAdd(&acc[g], lacc[tid]);
  }
}

template <int CIN, int COUT, int OT, bool HAS_BIAS, bool DO_LLR>
__global__ __launch_bounds__(256) void vn_apply(const float* __restrict__ X,
                                                const float* __restrict__ Wf,
                                                const float* __restrict__ Wd, int ws,
                                                const float* __restrict__ biasF,
                                                const float* __restrict__ biasD,
                                                const float* __restrict__ acc, float cntinv,
                                                float* __restrict__ OUT) {
  const int o0 = blockIdx.y * OT;
  const int t = blockIdx.x * 256 + threadIdx.x;
  const int n = t & (Nn - 1), b = t >> 13;
  const float* xb = X + (size_t)b * CIN * 3 * Nn + n;
  float* ob = OUT + (size_t)b * COUT * 3 * Nn + n;
  float p[OT][3], dv[OT][3];
#pragma unroll
  for (int j = 0; j < OT; ++j)
#pragma unroll
    for (int dd = 0; dd < 3; ++dd) {
      p[j][dd] = HAS_BIAS ? biasF[((size_t)b * COUT + o0 + j) * 3 + dd] : 0.f;
      if constexpr (DO_LLR)
        dv[j][dd] = HAS_BIAS ? biasD[((size_t)b * COUT + o0 + j) * 3 + dd] : 0.f;
      else
        dv[j][dd] = 0.f;
    }
  for (int c = 0; c < CIN; ++c) {
    const float x0 = xb[(c * 3 + 0) * Nn];
    const float x1v = xb[(c * 3 + 1) * Nn];
    const float x2v = xb[(c * 3 + 2) * Nn];
#pragma unroll
    for (int j = 0; j < OT; ++j) {
      const float wfv = Wf[(o0 + j) * ws + c];
      p[j][0] += wfv * x0; p[j][1] += wfv * x1v; p[j][2] += wfv * x2v;
      if constexpr (DO_LLR) {
        const float wdv = Wd[(o0 + j) * ws + c];
        dv[j][0] += wdv * x0; dv[j][1] += wdv * x1v; dv[j][2] += wdv * x2v;
      }
    }
  }
#pragma unroll
  for (int j = 0; j < OT; ++j) {
    const int o = o0 + j;
    const float nrm = sqrtf(p[j][0] * p[j][0] + p[j][1] * p[j][1] + p[j][2] * p[j][2]) + EPSF;
    const float mn = acc[o] * cntinv;
    const float vr = acc[COUT + o] * cntinv - mn * mn;
    const float factor = (nrm - mn) * rsqrtf(vr + BN_EPSF) / nrm;
    float r0 = p[j][0] * factor, r1 = p[j][1] * factor, r2 = p[j][2] * factor;
    if constexpr (DO_LLR) {
      const float dot = r0 * dv[j][0] + r1 * dv[j][1] + r2 * dv[j][2];
      const float dsq = dv[j][0] * dv[j][0] + dv[j][1] * dv[j][1] + dv[j][2] * dv[j][2];
      const float corr = (dot < 0.f) ? dot / (dsq + EPSF) : 0.f;
      r0 -= corr * dv[j][0]; r1 -= corr * dv[j][1]; r2 -= corr * dv[j][2];
    }
    ob[(o * 3 + 0) * Nn] = r0;
    ob[(o * 3 + 1) * Nn] = r1;
    ob[(o * 3 + 2) * Nn] = r2;
  }
}

// ---------------- stage 5: mean over N, bias precompute, small outputs ----------------
__global__ __launch_bounds__(256) void s5_mean(const float* __restrict__ x4,
                                               float* __restrict__ xm,
                                               float* __restrict__ out) {
  const int row = blockIdx.x;  // 0..1019 = b*255 + c*3 + dd
  const int b = row / 255, rcd = row % 255;
  const float* src = x4 + (size_t)b * 255 * Nn + (size_t)rcd * Nn;
  float s = 0.f;
  for (int n = threadIdx.x; n < Nn; n += 256) s += src[n];
  s = wave_sum(s);
  __shared__ float wsum[4];
  if ((threadIdx.x & 63) == 0) wsum[threadIdx.x >> 6] = s;
  __syncthreads();
  if (threadIdx.x == 0) {
    const float mv = (wsum[0] + wsum[1] + wsum[2] + wsum[3]) * (1.f / (float)Nn);
    xm[row] = mv;
    out[2040 + row] = mv;  // x_mean_out
  }
}

__global__ __launch_bounds__(256) void s5_bias(const float* __restrict__ xm,
                                               const float* __restrict__ ws1f,
                                               const float* __restrict__ ws1d,
                                               float* __restrict__ biasF,
                                               float* __restrict__ biasD,
                                               float* __restrict__ out) {
  const int t = blockIdx.x * 256 + threadIdx.x;
  if (t < 1020) {
    const int b = t / 255, r = t % 255, o = r / 3, dd = r % 3;
    float sf = 0.f, sd = 0.f;
    for (int c = 0; c < 85; ++c) {
      const float xv = xm[(b * 85 + c) * 3 + dd];
      sf += ws1f[o * 170 + 85 + c] * xv;
      sd += ws1d[o * 170 + 85 + c] * xv;
    }
    biasF[t] = sf;
    biasD[t] = sd;
  }
  if (t < 340) {
    const int b = t / 85, c = t % 85;
    out[3060 + t] = (xm[(b * 85 + c) * 3 + 0] + xm[(b * 85 + c) * 3 + 1] +
                     xm[(b * 85 + c) * 3 + 2]) * (1.f / 3.f);  // center_loc
  }
}

// ---------------- stage 8: z3 = wlin · z2 ----------------
__global__ __launch_bounds__(256) void s8_z3(const float* __restrict__ z2,
                                             const float* __restrict__ wlin,
                                             float* __restrict__ z3) {
  const int t = blockIdx.x * 256 + threadIdx.x;
  const int n = t & (Nn - 1), b = t >> 13;
  const float* zb = z2 + (size_t)b * 42 * 3 * Nn + n;
  float accv[3][3];
#pragma unroll
  for (int o = 0; o < 3; ++o)
#pragma unroll
    for (int dd = 0; dd < 3; ++dd) accv[o][dd] = 0.f;
  for (int c = 0; c < 42; ++c) {
    const float x0 = zb[(c * 3 + 0) * Nn];
    const float x1v = zb[(c * 3 + 1) * Nn];
    const float x2v = zb[(c * 3 + 2) * Nn];
#pragma unroll
    for (int o = 0; o < 3; ++o) {
      const float wv = wlin[o * 42 + c];
      accv[o][0] += wv * x0; accv[o][1] += wv * x1v; accv[o][2] += wv * x2v;
    }
  }
  float* ob = z3 + (size_t)b * 9 * Nn + n;
#pragma unroll
  for (int o = 0; o < 3; ++o)
#pragma unroll
    for (int dd = 0; dd < 3; ++dd) ob[(o * 3 + dd) * Nn] = accv[o][dd];
}

// ---------------- stage 9: x_std + max over N ----------------
__global__ __launch_bounds__(256) void s9_max(const float* __restrict__ x4,
                                              const float* __restrict__ xm,
                                              const float* __restrict__ z3,
                                              float* __restrict__ out) {
  const int tile = blockIdx.x;  // 0..33
  const int b = blockIdx.y;
  const int i0 = tile * 5;
  const bool upper = (i0 >= 85);
  float mx[15];
#pragma unroll
  for (int r = 0; r < 15; ++r) mx[r] = -3.402823466e38f;
  float xmr[5][3];
  if (upper) {
#pragma unroll
    for (int ii = 0; ii < 5; ++ii)
#pragma unroll
      for (int j = 0; j < 3; ++j) xmr[ii][j] = xm[(b * 85 + (i0 - 85 + ii)) * 3 + j];
  }
  const float* zb = z3 + (size_t)b * 9 * Nn;
  const float* xb = x4 + (size_t)b * 255 * Nn;
  for (int n = threadIdx.x; n < Nn; n += 256) {
    float zk[3][3];
#pragma unroll
    for (int k = 0; k < 3; ++k)
#pragma unroll
      for (int j = 0; j < 3; ++j) zk[k][j] = zb[(k * 3 + j) * Nn + n];
#pragma unroll
    for (int ii = 0; ii < 5; ++ii) {
      float xj0, xj1, xj2;
      if (upper) {
        xj0 = xmr[ii][0]; xj1 = xmr[ii][1]; xj2 = xmr[ii][2];
      } else {
        xj0 = xb[((i0 + ii) * 3 + 0) * Nn + n];
        xj1 = xb[((i0 + ii) * 3 + 1) * Nn + n];
        xj2 = xb[((i0 + ii) * 3 + 2) * Nn + n];
      }
#pragma unroll
      for (int k = 0; k < 3; ++k) {
        const float v = xj0 * zk[k][0] + xj1 * zk[k][1] + xj2 * zk[k][2];
        mx[ii * 3 + k] = fmaxf(mx[ii * 3 + k], v);
      }
    }
  }
  __shared__ float red[4 * 15];
#pragma unroll
  for (int r = 0; r < 15; ++r) {
    const float v = wave_max(mx[r]);
    if ((threadIdx.x & 63) == 0) red[(threadIdx.x >> 6) * 15 + r] = v;
  }
  __syncthreads();
  if (threadIdx.x < 15) {
    const float v = fmaxf(fmaxf(red[threadIdx.x], red[15 + threadIdx.x]),
                          fmaxf(red[30 + threadIdx.x], red[45 + threadIdx.x]));
    out[b * 510 + i0 * 3 + threadIdx.x] = v;
  }
}

// ---------------- launch ----------------
extern "C" void kernel_launch(void* const* d_in, const int* in_sizes, int n_in,
                              void* d_out, int out_size, void* d_ws, size_t ws_size,
                              hipStream_t stream) {
  const float* pts   = (const float*)d_in[0];
  const float* wposf = (const float*)d_in[1];
  const float* wposd = (const float*)d_in[2];
  const float* w1f   = (const float*)d_in[3];
  const float* w1d   = (const float*)d_in[4];
  const float* w2f   = (const float*)d_in[5];
  const float* w2d   = (const float*)d_in[6];
  const float* w3    = (const float*)d_in[7];
  const float* ws1f  = (const float*)d_in[8];
  const float* ws1d  = (const float*)d_in[9];
  const float* ws2f  = (const float*)d_in[10];
  const float* ws2d  = (const float*)d_in[11];
  const float* wlin  = (const float*)d_in[12];
  float* out = (float*)d_out;
  float* wsf = (float*)d_ws;

  uint32_t* knnp0 = (uint32_t*)(wsf + KNN0_OFF);
  uint32_t* knnp1 = (uint32_t*)(wsf + KNN1_OFF);
  float* x1 = wsf + X1_OFF;
  float* x2 = wsf + X2_OFF;
  float* x3 = wsf + X3_OFF;
  float* z1 = wsf + Z1_OFF;
  float* x4 = wsf + X4_OFF;
  int* idx  = (int*)(wsf + IDX_OFF);
  float* z2 = wsf + Z2_OFF;
  float* z3 = wsf + Z3_OFF;
  float* acc = wsf + ACC_OFF;
  float* xm = wsf + XM_OFF;
  float* biasF = wsf + BF_OFF;
  float* biasD = wsf + BD_OFF;

  const float inv_sites = 1.f / (float)(Bb * Nn);

  zero_acc<<<1, 1024, 0, stream>>>(acc);
  knn_kernel<<<dim3(Nn / 256, Bb, SEG), 128, 0, stream>>>(pts, knnp0);
  merge_pass<8><<<Bb * Nn * 4 / 256, 256, 0, stream>>>(knnp0, knnp1);
  merge_pass<4><<<Bb * Nn * 2 / 256, 256, 0, stream>>>(knnp1, knnp0);
  merge_final<<<Bb * Nn / 256, 256, 0, stream>>>(knnp0, idx);

  s1_stats<<<Bb * Nn * 5 / 256, 256, 0, stream>>>(pts, idx, wposf, acc + 0);
  s1_apply<<<dim3(Bb * Nn / 256, 3), 256, 0, stream>>>(pts, idx, wposf, wposd, acc + 0, x1);

  vn_stats<21, 21, 7, false><<<dim3(Bb * Nn / 256, 3), 256, 0, stream>>>(x1, w1f, 21, nullptr, acc + 64);
  vn_apply<21, 21, 7, false, true><<<dim3(Bb * Nn / 256, 3), 256, 0, stream>>>(
      x1, w1f, w1d, 21, nullptr, nullptr, acc + 64, inv_sites, x2);

  vn_stats<21, 42, 7, false><<<dim3(Bb * Nn / 256, 6), 256, 0, stream>>>(x2, w2f, 42, nullptr, acc + 128);
  vn_apply<21, 42, 7, false, true><<<dim3(Bb * Nn / 256, 6), 256, 0, stream>>>(
      x2, w2f, w2d, 42, nullptr, nullptr, acc + 128, inv_sites, x3);

  vn_stats<42, 85, 17, false><<<dim3(Bb * Nn / 256, 5), 256, 0, stream>>>(x3, w3, 42, nullptr, acc + 256);
  vn_apply<42, 85, 17, false, false><<<dim3(Bb * Nn / 256, 5), 256, 0, stream>>>(
      x3, w3, w3, 42, nullptr, nullptr, acc + 256, inv_sites, x4);

  s5_mean<<<Bb * 255, 256, 0, stream>>>(x4, xm, out);
  s5_bias<<<4, 256, 0, stream>>>(xm, ws1f, ws1d, biasF, biasD, out);

  vn_stats<85, 85, 17, true><<<dim3(Bb * Nn / 256, 5), 256, 0, stream>>>(x4, ws1f, 170, biasF, acc + 512);
  vn_apply<85, 85, 17, true, true><<<dim3(Bb * Nn / 256, 5), 256, 0, stream>>>(
      x4, ws1f, ws1d, 170, biasF, biasD, acc + 512, inv_sites, z1);

  vn_stats<85, 42, 14, false><<<dim3(Bb * Nn / 256, 3), 256, 0, stream>>>(z1, ws2f, 85, nullptr, acc + 768);
  vn_apply<85, 42, 14, false, true><<<dim3(Bb * Nn / 256, 3), 256, 0, stream>>>(
      z1, ws2f, ws2d, 85, nullptr, nullptr, acc + 768, inv_sites, z2);

  s8_z3<<<Bb * Nn / 256, 256, 0, stream>>>(z2, wlin, z3);
  s9_max<<<dim3(34, Bb), 256, 0, stream>>>(x4, xm, z3, out);
}

// Round 7
// 892.096 us; speedup vs baseline: 1.3423x; 1.0863x over previous
//
#include <hip/hip_runtime.h>
#include <cstdint>
#include <cstddef>

#define EPSF 1e-6f
#define BN_EPSF 1e-5f

constexpr int Bb = 4;
constexpr int Nn = 8192;
constexpr int KK = 20;
constexpr int SEG = 8;            // knn candidate segments
constexpr int SEGLEN = Nn / SEG;  // 1024
constexpr int BUF = 16;           // per-lane candidate buffer (LDS slots)

// ---------------- workspace layout (float elements) ----------------
constexpr size_t KNN0_OFF = 0;              // B*8*N*20 u32 = 5,242,880
constexpr size_t KNN1_OFF = 5242880;        // B*4*N*20 u32 = 2,621,440 (ends 7,864,320)
constexpr size_t X1_OFF  = 0;               // B*21*3*N = 2,064,384
constexpr size_t X2_OFF  = 2064384;
constexpr size_t X3_OFF  = 4128768;         // B*42*3*N = 4,128,768 (ends 8,257,536)
constexpr size_t Z1_OFF  = 0;               // B*85*3*N = 8,355,840
constexpr size_t X4_OFF  = 8355840;         // 8,355,840
constexpr size_t IDX_OFF = 16711680;        // B*N*K ints = 655,360
constexpr size_t Z2_OFF  = 17367040;        // 4,128,768
constexpr size_t Z3_OFF  = 21495808;        // B*3*3*N = 294,912
constexpr size_t ACC_OFF = 21790720;        // 1024
constexpr size_t XM_OFF  = 21791744;        // 1020
constexpr size_t BF_OFF  = 21792764;        // 1020
constexpr size_t BD_OFF  = 21793784;        // 1020

__device__ __forceinline__ float wave_sum(float v) {
#pragma unroll
  for (int off = 32; off; off >>= 1) v += __shfl_xor(v, off, 64);
  return v;
}
__device__ __forceinline__ float wave_max(float v) {
#pragma unroll
  for (int off = 32; off; off >>= 1) v = fmaxf(v, __shfl_xor(v, off, 64));
  return v;
}
__device__ __forceinline__ uint32_t umin32(uint32_t a, uint32_t b) { return a < b ? a : b; }
__device__ __forceinline__ uint32_t umax32(uint32_t a, uint32_t b) { return a < b ? b : a; }

// ---------------- zero accumulators ----------------
__global__ __launch_bounds__(1024) void zero_acc(float* __restrict__ a) {
  a[threadIdx.x] = 0.f;
}

// ---------------- KNN: buffered top-20 select over one segment ----------------
// Distance via dot identity: u = 0.5|q-c|^2 = (0.5|c|^2 + 0.5|q|^2) - q.c  (3 fma + add + clamp)
// key = (f32 u bits & 0xFFFFE000) | idx(13b) -> absolute order, merge-tree associative.
__global__ __launch_bounds__(256) void knn_kernel(const float* __restrict__ pts,
                                                  uint32_t* __restrict__ knnp) {
  __shared__ float4 tile[SEGLEN];          // 16 KB (xyz + 0.5|c|^2)
  __shared__ uint32_t buf[BUF * 256];      // 16 KB; buf[slot*256+tid] -> 2 lanes/bank, free
  const int tid = threadIdx.x;
  const int n = blockIdx.x * 256 + tid;
  const int b = blockIdx.y;
  const int s = blockIdx.z;
  const float* pb = pts + (size_t)b * Nn * 3;

  for (int i = tid; i < SEGLEN; i += 256) {
    const float* p = pb + (size_t)(s * SEGLEN + i) * 3;
    const float x = p[0], y = p[1], z = p[2];
    tile[i] = make_float4(x, y, z, 0.5f * (x * x + y * y + z * z));
  }
  const float qx = pb[n * 3 + 0], qy = pb[n * 3 + 1], qz = pb[n * 3 + 2];
  const float nqx = -qx, nqy = -qy, nqz = -qz;
  const float h = 0.5f * (qx * qx + qy * qy + qz * qz);
  __syncthreads();

  uint32_t keys[KK];
#pragma unroll
  for (int j = 0; j < KK; ++j) keys[j] = 0xFFFFFFFFu;

  const int base = s * SEGLEN;

  // ---- warm-up: first 64 candidates, direct min/max-chain insert ----
#pragma unroll 4
  for (int j = 0; j < 64; ++j) {
    const float4 c = tile[j];
    float u = fmaf(nqx, c.x, fmaf(nqy, c.y, fmaf(nqz, c.z, c.w + h)));
    u = fmaxf(u, 0.f);
    uint32_t mx = (__float_as_uint(u) & 0xFFFFE000u) | (uint32_t)(base + j);
#pragma unroll
    for (int q = 0; q < KK; ++q) {
      const uint32_t mn = umin32(keys[q], mx);
      mx = umax32(keys[q], mx);
      keys[q] = mn;
    }
  }

  uint32_t thresh = keys[KK - 1];
  int cnt = 0;

  // ---- main loop: screen against thresh, buffer survivors, merge rarely ----
  for (int j0 = 64; j0 < SEGLEN; j0 += 4) {
#pragma unroll
    for (int u4 = 0; u4 < 4; ++u4) {
      const int j = j0 + u4;
      const float4 c = tile[j];
      float u = fmaf(nqx, c.x, fmaf(nqy, c.y, fmaf(nqz, c.z, c.w + h)));
      u = fmaxf(u, 0.f);
      const uint32_t key = (__float_as_uint(u) & 0xFFFFE000u) | (uint32_t)(base + j);
      if (key < thresh) {
        buf[cnt * 256 + tid] = key;
        ++cnt;
      }
    }
    if (__any(cnt > BUF - 4)) {
#pragma unroll
      for (int i = 0; i < BUF; ++i) {
        uint32_t mx = (i < cnt) ? buf[i * 256 + tid] : 0xFFFFFFFFu;
#pragma unroll
        for (int q = 0; q < KK; ++q) {
          const uint32_t mn = umin32(keys[q], mx);
          mx = umax32(keys[q], mx);
          keys[q] = mn;
        }
      }
      cnt = 0;
      thresh = keys[KK - 1];
    }
  }
  // ---- final flush ----
#pragma unroll
  for (int i = 0; i < BUF; ++i) {
    uint32_t mx = (i < cnt) ? buf[i * 256 + tid] : 0xFFFFFFFFu;
#pragma unroll
    for (int q = 0; q < KK; ++q) {
      const uint32_t mn = umin32(keys[q], mx);
      mx = umax32(keys[q], mx);
      keys[q] = mn;
    }
  }

  // list-major layout: [(b*SEG+s)][j][n] -> coalesced stores per j
  uint32_t* op = knnp + ((size_t)(b * SEG + s) * KK) * Nn + n;
#pragma unroll
  for (int j = 0; j < KK; ++j) op[(size_t)j * Nn] = keys[j];
}

// ---------------- merge tree passes ----------------
template <int LIN>
__global__ __launch_bounds__(256) void merge_pass(const uint32_t* __restrict__ in,
                                                  uint32_t* __restrict__ out) {
  constexpr int LOUT = LIN / 2;
  const int t = blockIdx.x * 256 + threadIdx.x;  // B*N*LOUT threads
  const int n = t & (Nn - 1);
  const int r = t >> 13;
  const int j = r % LOUT, b = r / LOUT;
  const uint32_t* p0 = in + ((size_t)(b * LIN + 2 * j) * KK) * Nn + n;
  const uint32_t* p1 = in + ((size_t)(b * LIN + 2 * j + 1) * KK) * Nn + n;
  uint32_t* op = out + ((size_t)(b * LOUT + j) * KK) * Nn + n;
  int i0 = 0, i1 = 0;
  uint32_t k0 = p0[0], k1 = p1[0];
#pragma unroll
  for (int m = 0; m < KK; ++m) {
    uint32_t k;
    if (k0 <= k1) { k = k0; ++i0; k0 = (i0 < KK) ? p0[(size_t)i0 * Nn] : 0xFFFFFFFFu; }
    else          { k = k1; ++i1; k1 = (i1 < KK) ? p1[(size_t)i1 * Nn] : 0xFFFFFFFFu; }
    op[(size_t)m * Nn] = k;
  }
}

__global__ __launch_bounds__(256) void merge_final(const uint32_t* __restrict__ in,
                                                   int* __restrict__ idx) {
  const int t = blockIdx.x * 256 + threadIdx.x;  // B*N threads
  const int n = t & (Nn - 1), b = t >> 13;
  const uint32_t* p0 = in + ((size_t)(b * 2 + 0) * KK) * Nn + n;
  const uint32_t* p1 = in + ((size_t)(b * 2 + 1) * KK) * Nn + n;
  int* op = idx + (size_t)t * KK;
  int i0 = 0, i1 = 0;
  uint32_t k0 = p0[0], k1 = p1[0];
#pragma unroll
  for (int m = 0; m < KK; ++m) {
    uint32_t k;
    if (k0 <= k1) { k = k0; ++i0; k0 = (i0 < KK) ? p0[(size_t)i0 * Nn] : 0xFFFFFFFFu; }
    else          { k = k1; ++i1; k1 = (i1 < KK) ? p1[(size_t)i1 * Nn] : 0xFFFFFFFFu; }
    op[m] = (int)(k & 8191u);
  }
}

// ---------------- stage 1: feature-cross + LLR(21) ----------------
// 4 neighbors per thread: 4x fewer same-address atomics and wave_sum chains.
__global__ __launch_bounds__(256) void s1_stats(const float* __restrict__ pts,
                                                const int* __restrict__ idx,
                                                const float* __restrict__ wf,
                                                float* __restrict__ acc) {
  __shared__ float lacc[42];
  const int tid = threadIdx.x;
  for (int i = tid; i < 42; i += 256) lacc[i] = 0.f;
  __syncthreads();
  const int t = blockIdx.x * 256 + tid;  // 0..B*N*5-1
  const int site = t / 5;
  const int kq = (t % 5) * 4;
  const int n = site & (Nn - 1), b = site >> 13;
  const float* pb = pts + (size_t)b * Nn * 3;
  const float cx = pb[n * 3 + 0], cy = pb[n * 3 + 1], cz = pb[n * 3 + 2];
  float s1a[21], s2a[21];
#pragma unroll
  for (int o = 0; o < 21; ++o) { s1a[o] = 0.f; s2a[o] = 0.f; }
#pragma unroll
  for (int k = kq; k < kq + 4; ++k) {
    const int m = idx[(size_t)site * KK + k];
    const float ax = pb[m * 3 + 0], ay = pb[m * 3 + 1], az = pb[m * 3 + 2];
    const float e0x = ax - cx, e0y = ay - cy, e0z = az - cz;
    const float e2x = ay * cz - az * cy, e2y = az * cx - ax * cz, e2z = ax * cy - ay * cx;
#pragma unroll
    for (int o = 0; o < 21; ++o) {
      const float w0 = wf[o * 3 + 0], w1 = wf[o * 3 + 1], w2 = wf[o * 3 + 2];
      const float px = w0 * e0x + w1 * cx + w2 * e2x;
      const float py = w0 * e0y + w1 * cy + w2 * e2y;
      const float pz = w0 * e0z + w1 * cz + w2 * e2z;
      const float nrm = sqrtf(px * px + py * py + pz * pz) + EPSF;
      s1a[o] += nrm;
      s2a[o] += nrm * nrm;
    }
  }
#pragma unroll
  for (int o = 0; o < 21; ++o) {
    const float s1 = wave_sum(s1a[o]);
    const float s2 = wave_sum(s2a[o]);
    if ((tid & 63) == 0) { atomicAdd(&lacc[o], s1); atomicAdd(&lacc[21 + o], s2); }
  }
  __syncthreads();
  for (int i = tid; i < 42; i += 256) atomicAdd(&acc[i], lacc[i]);
}

// tile of 7 output channels per block (blockIdx.y)
__global__ __launch_bounds__(256) void s1_apply(const float* __restrict__ pts,
                                                const int* __restrict__ idx,
                                                const float* __restrict__ wf,
                                                const float* __restrict__ wd,
                                                const float* __restrict__ acc,
                                                float* __restrict__ x1) {
  const int t = blockIdx.x * 256 + threadIdx.x;  // site 0..B*N-1
  const int o0 = blockIdx.y * 7;
  const int n = t & (Nn - 1), b = t >> 13;
  const float* pb = pts + (size_t)b * Nn * 3;
  const float cx = pb[n * 3 + 0], cy = pb[n * 3 + 1], cz = pb[n * 3 + 2];
  const float inv_cnt = 1.f / (float)(Bb * Nn * KK);
  float meano[7], istdo[7];
#pragma unroll
  for (int j = 0; j < 7; ++j) {
    const float mn = acc[o0 + j] * inv_cnt;
    const float vr = acc[21 + o0 + j] * inv_cnt - mn * mn;
    meano[j] = mn;
    istdo[j] = rsqrtf(vr + BN_EPSF);
  }
  float accu[7][3];
#pragma unroll
  for (int j = 0; j < 7; ++j) { accu[j][0] = 0.f; accu[j][1] = 0.f; accu[j][2] = 0.f; }
  for (int k = 0; k < KK; ++k) {
    const int m = idx[(size_t)t * KK + k];
    const float ax = pb[m * 3 + 0], ay = pb[m * 3 + 1], az = pb[m * 3 + 2];
    const float e0x = ax - cx, e0y = ay - cy, e0z = az - cz;
    const float e2x = ay * cz - az * cy, e2y = az * cx - ax * cz, e2z = ax * cy - ay * cx;
#pragma unroll
    for (int j = 0; j < 7; ++j) {
      const int o = o0 + j;
      const float wf0 = wf[o * 3 + 0], wf1 = wf[o * 3 + 1], wf2 = wf[o * 3 + 2];
      const float px = wf0 * e0x + wf1 * cx + wf2 * e2x;
      const float py = wf0 * e0y + wf1 * cy + wf2 * e2y;
      const float pz = wf0 * e0z + wf1 * cz + wf2 * e2z;
      const float nrm = sqrtf(px * px + py * py + pz * pz) + EPSF;
      const float factor = (nrm - meano[j]) * istdo[j] / nrm;
      const float q0 = px * factor, q1 = py * factor, q2 = pz * factor;
      const float wd0 = wd[o * 3 + 0], wd1 = wd[o * 3 + 1], wd2 = wd[o * 3 + 2];
      const float dx = wd0 * e0x + wd1 * cx + wd2 * e2x;
      const float dy = wd0 * e0y + wd1 * cy + wd2 * e2y;
      const float dz = wd0 * e0z + wd1 * cz + wd2 * e2z;
      const float dot = q0 * dx + q1 * dy + q2 * dz;
      const float dsq = dx * dx + dy * dy + dz * dz;
      const float corr = (dot < 0.f) ? dot / (dsq + EPSF) : 0.f;
      accu[j][0] += q0 - corr * dx;
      accu[j][1] += q1 - corr * dy;
      accu[j][2] += q2 - corr * dz;
    }
  }
  const float sc = 1.f / (float)KK;
  float* ob = x1 + (size_t)b * 21 * 3 * Nn + n;
#pragma unroll
  for (int j = 0; j < 7; ++j) {
    const int o = o0 + j;
    ob[(o * 3 + 0) * Nn] = accu[j][0] * sc;
    ob[(o * 3 + 1) * Nn] = accu[j][1] * sc;
    ob[(o * 3 + 2) * Nn] = accu[j][2] * sc;
  }
}

// ---------------- generic VN layer: stats + apply (o-tile = blockIdx.y) ----------------
template <int CIN, int COUT, int OT, bool HAS_BIAS>
__global__ __launch_bounds__(256) void vn_stats(const float* __restrict__ X,
                                                const float* __restrict__ Wf, int ws,
                                                const float* __restrict__ biasF,
                                                float* __restrict__ acc) {
  __shared__ float lacc[2 * OT];
  const int tid = threadIdx.x;
  if (tid < 2 * OT) lacc[tid] = 0.f;
  __syncthreads();
  const int o0 = blockIdx.y * OT;
  const int t = blockIdx.x * 256 + tid;
  const int n = t & (Nn - 1), b = t >> 13;
  const float* xb = X + (size_t)b * CIN * 3 * Nn + n;
  float p[OT][3];
#pragma unroll
  for (int j = 0; j < OT; ++j)
#pragma unroll
    for (int dd = 0; dd < 3; ++dd)
      p[j][dd] = HAS_BIAS ? biasF[((size_t)b * COUT + o0 + j) * 3 + dd] : 0.f;
  for (int c = 0; c < CIN; ++c) {
    const float x0 = xb[(c * 3 + 0) * Nn];
    const float x1v = xb[(c * 3 + 1) * Nn];
    const float x2v = xb[(c * 3 + 2) * Nn];
#pragma unroll
    for (int j = 0; j < OT; ++j) {
      const float wv = Wf[(o0 + j) * ws + c];
      p[j][0] += wv * x0; p[j][1] += wv * x1v; p[j][2] += wv * x2v;
    }
  }
#pragma unroll
  for (int j = 0; j < OT; ++j) {
    const float nrm = sqrtf(p[j][0] * p[j][0] + p[j][1] * p[j][1] + p[j][2] * p[j][2]) + EPSF;
    const float s1 = wave_sum(nrm);
    const float s2 = wave_sum(nrm * nrm);
    if ((tid & 63) == 0) { atomicAdd(&lacc[j], s1); atomicAdd(&lacc[OT + j], s2); }
  }
  __syncthreads();
  if (tid < 2 * OT) {
    const int g = (tid < OT) ? (o0 + tid) : (COUT + o0 + (tid - OT));
    atomicAdd(&acc[g], lacc[tid]);
  }
}

template <int CIN, int COUT, int OT, bool HAS_BIAS, bool DO_LLR>
__global__ __launch_bounds__(256) void vn_apply(const float* __restrict__ X,
                                                const float* __restrict__ Wf,
                                                const float* __restrict__ Wd, int ws,
                                                const float* __restrict__ biasF,
                                                const float* __restrict__ biasD,
                                                const float* __restrict__ acc, float cntinv,
                                                float* __restrict__ OUT) {
  const int o0 = blockIdx.y * OT;
  const int t = blockIdx.x * 256 + threadIdx.x;
  const int n = t & (Nn - 1), b = t >> 13;
  const float* xb = X + (size_t)b * CIN * 3 * Nn + n;
  float* ob = OUT + (size_t)b * COUT * 3 * Nn + n;
  float p[OT][3], dv[OT][3];
#pragma unroll
  for (int j = 0; j < OT; ++j)
#pragma unroll
    for (int dd = 0; dd < 3; ++dd) {
      p[j][dd] = HAS_BIAS ? biasF[((size_t)b * COUT + o0 + j) * 3 + dd] : 0.f;
      if constexpr (DO_LLR)
        dv[j][dd] = HAS_BIAS ? biasD[((size_t)b * COUT + o0 + j) * 3 + dd] : 0.f;
      else
        dv[j][dd] = 0.f;
    }
  for (int c = 0; c < CIN; ++c) {
    const float x0 = xb[(c * 3 + 0) * Nn];
    const float x1v = xb[(c * 3 + 1) * Nn];
    const float x2v = xb[(c * 3 + 2) * Nn];
#pragma unroll
    for (int j = 0; j < OT; ++j) {
      const float wfv = Wf[(o0 + j) * ws + c];
      p[j][0] += wfv * x0; p[j][1] += wfv * x1v; p[j][2] += wfv * x2v;
      if constexpr (DO_LLR) {
        const float wdv = Wd[(o0 + j) * ws + c];
        dv[j][0] += wdv * x0; dv[j][1] += wdv * x1v; dv[j][2] += wdv * x2v;
      }
    }
  }
#pragma unroll
  for (int j = 0; j < OT; ++j) {
    const int o = o0 + j;
    const float nrm = sqrtf(p[j][0] * p[j][0] + p[j][1] * p[j][1] + p[j][2] * p[j][2]) + EPSF;
    const float mn = acc[o] * cntinv;
    const float vr = acc[COUT + o] * cntinv - mn * mn;
    const float factor = (nrm - mn) * rsqrtf(vr + BN_EPSF) / nrm;
    float r0 = p[j][0] * factor, r1 = p[j][1] * factor, r2 = p[j][2] * factor;
    if constexpr (DO_LLR) {
      const float dot = r0 * dv[j][0] + r1 * dv[j][1] + r2 * dv[j][2];
      const float dsq = dv[j][0] * dv[j][0] + dv[j][1] * dv[j][1] + dv[j][2] * dv[j][2];
      const float corr = (dot < 0.f) ? dot / (dsq + EPSF) : 0.f;
      r0 -= corr * dv[j][0]; r1 -= corr * dv[j][1]; r2 -= corr * dv[j][2];
    }
    ob[(o * 3 + 0) * Nn] = r0;
    ob[(o * 3 + 1) * Nn] = r1;
    ob[(o * 3 + 2) * Nn] = r2;
  }
}

// ---------------- stage 5: mean over N, bias precompute, small outputs ----------------
__global__ __launch_bounds__(256) void s5_mean(const float* __restrict__ x4,
                                               float* __restrict__ xm,
                                               float* __restrict__ out) {
  const int row = blockIdx.x;  // 0..1019 = b*255 + c*3 + dd
  const int b = row / 255, rcd = row % 255;
  const float* src = x4 + (size_t)b * 255 * Nn + (size_t)rcd * Nn;
  float s = 0.f;
  for (int n = threadIdx.x; n < Nn; n += 256) s += src[n];
  s = wave_sum(s);
  __shared__ float wsum[4];
  if ((threadIdx.x & 63) == 0) wsum[threadIdx.x >> 6] = s;
  __syncthreads();
  if (threadIdx.x == 0) {
    const float mv = (wsum[0] + wsum[1] + wsum[2] + wsum[3]) * (1.f / (float)Nn);
    xm[row] = mv;
    out[2040 + row] = mv;  // x_mean_out
  }
}

__global__ __launch_bounds__(256) void s5_bias(const float* __restrict__ xm,
                                               const float* __restrict__ ws1f,
                                               const float* __restrict__ ws1d,
                                               float* __restrict__ biasF,
                                               float* __restrict__ biasD,
                                               float* __restrict__ out) {
  const int t = blockIdx.x * 256 + threadIdx.x;
  if (t < 1020) {
    const int b = t / 255, r = t % 255, o = r / 3, dd = r % 3;
    float sf = 0.f, sd = 0.f;
    for (int c = 0; c < 85; ++c) {
      const float xv = xm[(b * 85 + c) * 3 + dd];
      sf += ws1f[o * 170 + 85 + c] * xv;
      sd += ws1d[o * 170 + 85 + c] * xv;
    }
    biasF[t] = sf;
    biasD[t] = sd;
  }
  if (t < 340) {
    const int b = t / 85, c = t % 85;
    out[3060 + t] = (xm[(b * 85 + c) * 3 + 0] + xm[(b * 85 + c) * 3 + 1] +
                     xm[(b * 85 + c) * 3 + 2]) * (1.f / 3.f);  // center_loc
  }
}

// ---------------- stage 8: z3 = wlin · z2 ----------------
__global__ __launch_bounds__(256) void s8_z3(const float* __restrict__ z2,
                                             const float* __restrict__ wlin,
                                             float* __restrict__ z3) {
  const int t = blockIdx.x * 256 + threadIdx.x;
  const int n = t & (Nn - 1), b = t >> 13;
  const float* zb = z2 + (size_t)b * 42 * 3 * Nn + n;
  float accv[3][3];
#pragma unroll
  for (int o = 0; o < 3; ++o)
#pragma unroll
    for (int dd = 0; dd < 3; ++dd) accv[o][dd] = 0.f;
  for (int c = 0; c < 42; ++c) {
    const float x0 = zb[(c * 3 + 0) * Nn];
    const float x1v = zb[(c * 3 + 1) * Nn];
    const float x2v = zb[(c * 3 + 2) * Nn];
#pragma unroll
    for (int o = 0; o < 3; ++o) {
      const float wv = wlin[o * 42 + c];
      accv[o][0] += wv * x0; accv[o][1] += wv * x1v; accv[o][2] += wv * x2v;
    }
  }
  float* ob = z3 + (size_t)b * 9 * Nn + n;
#pragma unroll
  for (int o = 0; o < 3; ++o)
#pragma unroll
    for (int dd = 0; dd < 3; ++dd) ob[(o * 3 + dd) * Nn] = accv[o][dd];
}

// ---------------- stage 9: x_std + max over N ----------------
__global__ __launch_bounds__(256) void s9_max(const float* __restrict__ x4,
                                              const float* __restrict__ xm,
                                              const float* __restrict__ z3,
                                              float* __restrict__ out) {
  const int tile = blockIdx.x;  // 0..33
  const int b = blockIdx.y;
  const int i0 = tile * 5;
  const bool upper = (i0 >= 85);
  float mx[15];
#pragma unroll
  for (int r = 0; r < 15; ++r) mx[r] = -3.402823466e38f;
  float xmr[5][3];
  if (upper) {
#pragma unroll
    for (int ii = 0; ii < 5; ++ii)
#pragma unroll
      for (int j = 0; j < 3; ++j) xmr[ii][j] = xm[(b * 85 + (i0 - 85 + ii)) * 3 + j];
  }
  const float* zb = z3 + (size_t)b * 9 * Nn;
  const float* xb = x4 + (size_t)b * 255 * Nn;
  for (int n = threadIdx.x; n < Nn; n += 256) {
    float zk[3][3];
#pragma unroll
    for (int k = 0; k < 3; ++k)
#pragma unroll
      for (int j = 0; j < 3; ++j) zk[k][j] = zb[(k * 3 + j) * Nn + n];
#pragma unroll
    for (int ii = 0; ii < 5; ++ii) {
      float xj0, xj1, xj2;
      if (upper) {
        xj0 = xmr[ii][0]; xj1 = xmr[ii][1]; xj2 = xmr[ii][2];
      } else {
        xj0 = xb[((i0 + ii) * 3 + 0) * Nn + n];
        xj1 = xb[((i0 + ii) * 3 + 1) * Nn + n];
        xj2 = xb[((i0 + ii) * 3 + 2) * Nn + n];
      }
#pragma unroll
      for (int k = 0; k < 3; ++k) {
        const float v = xj0 * zk[k][0] + xj1 * zk[k][1] + xj2 * zk[k][2];
        mx[ii * 3 + k] = fmaxf(mx[ii * 3 + k], v);
      }
    }
  }
  __shared__ float red[4 * 15];
#pragma unroll
  for (int r = 0; r < 15; ++r) {
    const float v = wave_max(mx[r]);
    if ((threadIdx.x & 63) == 0) red[(threadIdx.x >> 6) * 15 + r] = v;
  }
  __syncthreads();
  if (threadIdx.x < 15) {
    const float v = fmaxf(fmaxf(red[threadIdx.x], red[15 + threadIdx.x]),
                          fmaxf(red[30 + threadIdx.x], red[45 + threadIdx.x]));
    out[b * 510 + i0 * 3 + threadIdx.x] = v;
  }
}

// ---------------- launch ----------------
extern "C" void kernel_launch(void* const* d_in, const int* in_sizes, int n_in,
                              void* d_out, int out_size, void* d_ws, size_t ws_size,
                              hipStream_t stream) {
  const float* pts   = (const float*)d_in[0];
  const float* wposf = (const float*)d_in[1];
  const float* wposd = (const float*)d_in[2];
  const float* w1f   = (const float*)d_in[3];
  const float* w1d   = (const float*)d_in[4];
  const float* w2f   = (const float*)d_in[5];
  const float* w2d   = (const float*)d_in[6];
  const float* w3    = (const float*)d_in[7];
  const float* ws1f  = (const float*)d_in[8];
  const float* ws1d  = (const float*)d_in[9];
  const float* ws2f  = (const float*)d_in[10];
  const float* ws2d  = (const float*)d_in[11];
  const float* wlin  = (const float*)d_in[12];
  float* out = (float*)d_out;
  float* wsf = (float*)d_ws;

  uint32_t* knnp0 = (uint32_t*)(wsf + KNN0_OFF);
  uint32_t* knnp1 = (uint32_t*)(wsf + KNN1_OFF);
  float* x1 = wsf + X1_OFF;
  float* x2 = wsf + X2_OFF;
  float* x3 = wsf + X3_OFF;
  float* z1 = wsf + Z1_OFF;
  float* x4 = wsf + X4_OFF;
  int* idx  = (int*)(wsf + IDX_OFF);
  float* z2 = wsf + Z2_OFF;
  float* z3 = wsf + Z3_OFF;
  float* acc = wsf + ACC_OFF;
  float* xm = wsf + XM_OFF;
  float* biasF = wsf + BF_OFF;
  float* biasD = wsf + BD_OFF;

  const float inv_sites = 1.f / (float)(Bb * Nn);

  zero_acc<<<1, 1024, 0, stream>>>(acc);
  knn_kernel<<<dim3(Nn / 256, Bb, SEG), 256, 0, stream>>>(pts, knnp0);
  merge_pass<8><<<Bb * Nn * 4 / 256, 256, 0, stream>>>(knnp0, knnp1);
  merge_pass<4><<<Bb * Nn * 2 / 256, 256, 0, stream>>>(knnp1, knnp0);
  merge_final<<<Bb * Nn / 256, 256, 0, stream>>>(knnp0, idx);

  s1_stats<<<Bb * Nn * 5 / 256, 256, 0, stream>>>(pts, idx, wposf, acc + 0);
  s1_apply<<<dim3(Bb * Nn / 256, 3), 256, 0, stream>>>(pts, idx, wposf, wposd, acc + 0, x1);

  vn_stats<21, 21, 7, false><<<dim3(Bb * Nn / 256, 3), 256, 0, stream>>>(x1, w1f, 21, nullptr, acc + 64);
  vn_apply<21, 21, 7, false, true><<<dim3(Bb * Nn / 256, 3), 256, 0, stream>>>(
      x1, w1f, w1d, 21, nullptr, nullptr, acc + 64, inv_sites, x2);

  vn_stats<21, 42, 7, false><<<dim3(Bb * Nn / 256, 6), 256, 0, stream>>>(x2, w2f, 42, nullptr, acc + 128);
  vn_apply<21, 42, 7, false, true><<<dim3(Bb * Nn / 256, 6), 256, 0, stream>>>(
      x2, w2f, w2d, 42, nullptr, nullptr, acc + 128, inv_sites, x3);

  vn_stats<42, 85, 17, false><<<dim3(Bb * Nn / 256, 5), 256, 0, stream>>>(x3, w3, 42, nullptr, acc + 256);
  vn_apply<42, 85, 17, false, false><<<dim3(Bb * Nn / 256, 5), 256, 0, stream>>>(
      x3, w3, w3, 42, nullptr, nullptr, acc + 256, inv_sites, x4);

  s5_mean<<<Bb * 255, 256, 0, stream>>>(x4, xm, out);
  s5_bias<<<4, 256, 0, stream>>>(xm, ws1f, ws1d, biasF, biasD, out);

  vn_stats<85, 85, 17, true><<<dim3(Bb * Nn / 256, 5), 256, 0, stream>>>(x4, ws1f, 170, biasF, acc + 512);
  vn_apply<85, 85, 17, true, true><<<dim3(Bb * Nn / 256, 5), 256, 0, stream>>>(
      x4, ws1f, ws1d, 170, biasF, biasD, acc + 512, inv_sites, z1);

  vn_stats<85, 42, 14, false><<<dim3(Bb * Nn / 256, 3), 256, 0, stream>>>(z1, ws2f, 85, nullptr, acc + 768);
  vn_apply<85, 42, 14, false, true><<<dim3(Bb * Nn / 256, 3), 256, 0, stream>>>(
      z1, ws2f, ws2d, 85, nullptr, nullptr, acc + 768, inv_sites, z2);

  s8_z3<<<Bb * Nn / 256, 256, 0, stream>>>(z2, wlin, z3);
  s9_max<<<dim3(34, Bb), 256, 0, stream>>>(x4, xm, z3, out);
}